// Round 1
// baseline (618.781 us; speedup 1.0000x reference)
//
#include <hip/hip_runtime.h>
#include <hip/hip_bf16.h>

// ---------------------------------------------------------------------------
// 2-layer GCN: out = GCN(relu(GCN(x, W1)+b1... ), W2) + b2
// Refactor: per layer, g[j] = dinv[j] * (X @ W)[j];  out[i] = dinv[i] * (g[i] + sum_{j->i} g[j]) + b
// Graph built once as CSR-by-destination; reused by both layers.
// ---------------------------------------------------------------------------

__global__ void zero_i32(int* __restrict__ p, int n) {
    int i = blockIdx.x * blockDim.x + threadIdx.x;
    if (i < n) p[i] = 0;
}

__global__ void hist_kernel(const int* __restrict__ dst, int* __restrict__ cnt, int E) {
    int stride = gridDim.x * blockDim.x;
    for (int e = blockIdx.x * blockDim.x + threadIdx.x; e < E; e += stride)
        atomicAdd(&cnt[dst[e]], 1);
}

__global__ void dinv_kernel(const int* __restrict__ cnt, float* __restrict__ dinv, int N) {
    int i = blockIdx.x * blockDim.x + threadIdx.x;
    if (i < N) dinv[i] = rsqrtf((float)(cnt[i] + 1));   // +1 = self-loop; deg >= 1 always
}

// Single-block exclusive scan over N counts -> offs[0..N], and curs = copy of offs.
__global__ __launch_bounds__(1024) void scan_kernel(const int* __restrict__ cnt,
                                                    int* __restrict__ offs,
                                                    int* __restrict__ curs, int N) {
    __shared__ int tmp[1024];
    __shared__ int base_s;
    int tid = threadIdx.x;
    if (tid == 0) base_s = 0;
    __syncthreads();
    for (int start = 0; start < N; start += 1024) {
        int i = start + tid;
        int v = (i < N) ? cnt[i] : 0;
        tmp[tid] = v;
        __syncthreads();
        int sum = v;
        for (int off = 1; off < 1024; off <<= 1) {
            int t = (tid >= off) ? tmp[tid - off] : 0;
            __syncthreads();
            sum += t;
            tmp[tid] = sum;
            __syncthreads();
        }
        int excl = sum - v;
        int base = base_s;
        if (i < N) { offs[i] = base + excl; curs[i] = base + excl; }
        __syncthreads();
        if (tid == 1023) base_s = base + sum;
        __syncthreads();
    }
    if (tid == 0) offs[N] = base_s;
}

__global__ void scatter_kernel(const int* __restrict__ src, const int* __restrict__ dst,
                               int* __restrict__ curs, int* __restrict__ csr, int E) {
    int stride = gridDim.x * blockDim.x;
    for (int e = blockIdx.x * blockDim.x + threadIdx.x; e < E; e += stride) {
        int d = dst[e];
        int p = atomicAdd(&curs[d], 1);
        csr[p] = src[e];
    }
}

// G[r, c] = dinv[r] * sum_k X[r,k] * W[k,c].   K fixed at 128.
// Block: 256 threads, 64 rows. Thread tile: 4 rows x (COUT/16) cols.
template <int COUT>
__global__ __launch_bounds__(256) void gemm_scale(const float* __restrict__ X,
                                                  const float* __restrict__ W,
                                                  const float* __restrict__ dinv,
                                                  float* __restrict__ G, int N) {
    constexpr int K = 128, BR = 64, KC = 32;
    constexpr int CPT = COUT / 16;   // 8 (COUT=128) or 4 (COUT=64)
    __shared__ float sx[KC][BR];     // x transposed: [k][row]
    __shared__ float sw[KC][COUT];
    const int tid = threadIdx.x;
    const int tx = tid & 15;   // col group
    const int ty = tid >> 4;   // row group (4 rows each)
    const int r0 = blockIdx.x * BR;

    float acc[4][CPT];
#pragma unroll
    for (int i = 0; i < 4; ++i)
#pragma unroll
        for (int j = 0; j < CPT; ++j) acc[i][j] = 0.f;

    const int lr = tid >> 2;          // 0..63: row within tile for staging
    const int lk = (tid & 3) * 8;     // 0,8,16,24: k offset for staging
    const int gr = min(r0 + lr, N - 1);

    for (int kc = 0; kc < K; kc += KC) {
        float4 a = *reinterpret_cast<const float4*>(&X[(size_t)gr * K + kc + lk]);
        float4 b = *reinterpret_cast<const float4*>(&X[(size_t)gr * K + kc + lk + 4]);
        sx[lk + 0][lr] = a.x; sx[lk + 1][lr] = a.y; sx[lk + 2][lr] = a.z; sx[lk + 3][lr] = a.w;
        sx[lk + 4][lr] = b.x; sx[lk + 5][lr] = b.y; sx[lk + 6][lr] = b.z; sx[lk + 7][lr] = b.w;
        constexpr int NF4 = (KC * COUT) / (256 * 4);
#pragma unroll
        for (int q = 0; q < NF4; ++q) {
            int f = tid + q * 256;
            int kk = (f * 4) / COUT;
            int cc = (f * 4) % COUT;
            *reinterpret_cast<float4*>(&sw[kk][cc]) =
                *reinterpret_cast<const float4*>(&W[(size_t)(kc + kk) * COUT + cc]);
        }
        __syncthreads();
#pragma unroll
        for (int k = 0; k < KC; ++k) {
            float xv[4];
#pragma unroll
            for (int i = 0; i < 4; ++i) xv[i] = sx[k][ty * 4 + i];
            float wv[CPT];
#pragma unroll
            for (int j = 0; j < CPT; j += 4)
                *reinterpret_cast<float4*>(&wv[j]) =
                    *reinterpret_cast<float4*>(&sw[k][tx * CPT + j]);
#pragma unroll
            for (int i = 0; i < 4; ++i)
#pragma unroll
                for (int j = 0; j < CPT; ++j) acc[i][j] += xv[i] * wv[j];
        }
        __syncthreads();
    }
#pragma unroll
    for (int i = 0; i < 4; ++i) {
        int r = r0 + ty * 4 + i;
        if (r < N) {
            float di = dinv[r];
#pragma unroll
            for (int j = 0; j < CPT; j += 4) {
                float4 o;
                o.x = acc[i][j + 0] * di;
                o.y = acc[i][j + 1] * di;
                o.z = acc[i][j + 2] * di;
                o.w = acc[i][j + 3] * di;
                *reinterpret_cast<float4*>(&G[(size_t)r * COUT + tx * CPT + j]) = o;
            }
        }
    }
}

// One wave per node. VEC=2 -> C=128 (float2/lane); VEC=1 -> C=64 (float/lane).
template <int VEC, bool RELU>
__global__ __launch_bounds__(256) void agg_kernel(const float* __restrict__ G,
                                                  const int* __restrict__ offs,
                                                  const int* __restrict__ csr,
                                                  const float* __restrict__ dinv,
                                                  const float* __restrict__ bias,
                                                  float* __restrict__ out, int N) {
    int node = (blockIdx.x * blockDim.x + threadIdx.x) >> 6;
    int lane = threadIdx.x & 63;
    if (node >= N) return;
    int e = offs[node];
    const int end = offs[node + 1];
    if constexpr (VEC == 2) {
        const float2* Gp = reinterpret_cast<const float2*>(G);
        float2 s = Gp[(size_t)node * 64 + lane];   // self-loop term
        float ax = s.x, ay = s.y;
        for (; e + 4 <= end; e += 4) {
            int j0 = csr[e], j1 = csr[e + 1], j2 = csr[e + 2], j3 = csr[e + 3];
            float2 v0 = Gp[(size_t)j0 * 64 + lane];
            float2 v1 = Gp[(size_t)j1 * 64 + lane];
            float2 v2 = Gp[(size_t)j2 * 64 + lane];
            float2 v3 = Gp[(size_t)j3 * 64 + lane];
            ax += v0.x + v1.x + v2.x + v3.x;
            ay += v0.y + v1.y + v2.y + v3.y;
        }
        for (; e < end; ++e) {
            int j = csr[e];
            float2 v = Gp[(size_t)j * 64 + lane];
            ax += v.x; ay += v.y;
        }
        float di = dinv[node];
        float ox = ax * di + bias[lane * 2 + 0];
        float oy = ay * di + bias[lane * 2 + 1];
        if (RELU) { ox = fmaxf(ox, 0.f); oy = fmaxf(oy, 0.f); }
        float2* Op = reinterpret_cast<float2*>(out);
        float2 o; o.x = ox; o.y = oy;
        Op[(size_t)node * 64 + lane] = o;
    } else {
        float acc = G[(size_t)node * 64 + lane];   // self-loop term
        for (; e + 4 <= end; e += 4) {
            int j0 = csr[e], j1 = csr[e + 1], j2 = csr[e + 2], j3 = csr[e + 3];
            float v0 = G[(size_t)j0 * 64 + lane];
            float v1 = G[(size_t)j1 * 64 + lane];
            float v2 = G[(size_t)j2 * 64 + lane];
            float v3 = G[(size_t)j3 * 64 + lane];
            acc += v0 + v1 + v2 + v3;
        }
        for (; e < end; ++e) acc += G[(size_t)csr[e] * 64 + lane];
        float o = acc * dinv[node] + bias[lane];
        if (RELU) o = fmaxf(o, 0.f);
        out[(size_t)node * 64 + lane] = o;
    }
}

extern "C" void kernel_launch(void* const* d_in, const int* in_sizes, int n_in,
                              void* d_out, int out_size, void* d_ws, size_t ws_size,
                              hipStream_t stream) {
    const float* x  = (const float*)d_in[0];
    const int*   ei = (const int*)d_in[1];    // harness delivers integer inputs as int32
    const float* W1 = (const float*)d_in[2];
    const float* b1 = (const float*)d_in[3];
    const float* W2 = (const float*)d_in[4];
    const float* b2 = (const float*)d_in[5];
    float* out = (float*)d_out;

    const int N = in_sizes[0] / 128;
    const int E = in_sizes[1] / 2;
    const int* src = ei;
    const int* dst = ei + E;

    // Workspace layout
    float* g1 = (float*)d_ws;                       // N*128 f32 (51.2 MB); later reused as g2 (N*64)
    float* a1 = g1 + (size_t)N * 128;               // N*128 f32 (51.2 MB)
    float* g2 = g1;
    char* p = (char*)(a1 + (size_t)N * 128);
    int* cnt = (int*)p;    p += (((size_t)N * 4) + 15) & ~(size_t)15;
    float* dinv = (float*)p; p += (((size_t)N * 4) + 15) & ~(size_t)15;
    int* offs = (int*)p;   p += (((size_t)(N + 1) * 4) + 15) & ~(size_t)15;
    int* curs = (int*)p;   p += (((size_t)N * 4) + 15) & ~(size_t)15;
    int* csr = (int*)p;    p += (((size_t)E * 4) + 15) & ~(size_t)15;
    if ((size_t)(p - (char*)d_ws) > ws_size) return;  // workspace too small: fail loudly

    // --- graph preprocessing (once, shared by both layers) ---
    zero_i32<<<(N + 255) / 256, 256, 0, stream>>>(cnt, N);
    hist_kernel<<<2048, 256, 0, stream>>>(dst, cnt, E);
    dinv_kernel<<<(N + 255) / 256, 256, 0, stream>>>(cnt, dinv, N);
    scan_kernel<<<1, 1024, 0, stream>>>(cnt, offs, curs, N);
    scatter_kernel<<<2048, 256, 0, stream>>>(src, dst, curs, csr, E);

    // --- layer 1 ---
    gemm_scale<128><<<(N + 63) / 64, 256, 0, stream>>>(x, W1, dinv, g1, N);
    agg_kernel<2, true><<<(N + 3) / 4, 256, 0, stream>>>(g1, offs, csr, dinv, b1, a1, N);

    // --- layer 2 ---
    gemm_scale<64><<<(N + 63) / 64, 256, 0, stream>>>(a1, W2, dinv, g2, N);
    agg_kernel<1, false><<<(N + 3) / 4, 256, 0, stream>>>(g2, offs, csr, dinv, b2, out, N);
}

// Round 2
// 476.720 us; speedup vs baseline: 1.2980x; 1.2980x over previous
//
#include <hip/hip_runtime.h>
#include <hip/hip_bf16.h>

// ---------------------------------------------------------------------------
// 2-layer GCN: out = GCN(relu(GCN(x, W1)+b1... ), W2) + b2
// Refactor: per layer, g[j] = dinv[j] * (X @ W)[j];  out[i] = dinv[i] * (g[i] + sum_{j->i} g[j]) + b
// Graph built once as CSR-by-destination; reused by both layers.
// R1: replaced 160us single-block scan with 3-phase hierarchical scan (~8us).
// ---------------------------------------------------------------------------

__global__ void zero_i32(int* __restrict__ p, int n) {
    int i = blockIdx.x * blockDim.x + threadIdx.x;
    if (i < n) p[i] = 0;
}

__global__ void hist_kernel(const int* __restrict__ dst, int* __restrict__ cnt, int E) {
    int stride = gridDim.x * blockDim.x;
    for (int e = blockIdx.x * blockDim.x + threadIdx.x; e < E; e += stride)
        atomicAdd(&cnt[dst[e]], 1);
}

__global__ void dinv_kernel(const int* __restrict__ cnt, float* __restrict__ dinv, int N) {
    int i = blockIdx.x * blockDim.x + threadIdx.x;
    if (i < N) dinv[i] = rsqrtf((float)(cnt[i] + 1));   // +1 = self-loop; deg >= 1 always
}

// --- hierarchical scan: phase 1 — per-block (1024 elems) exclusive scan + block sum
__global__ __launch_bounds__(256) void scan_local(const int* __restrict__ cnt,
                                                  int* __restrict__ offs,
                                                  int* __restrict__ bsums, int N) {
    __shared__ int tmp[256];
    const int tid = threadIdx.x;
    const int base = blockIdx.x * 1024 + tid * 4;
    int v[4];
#pragma unroll
    for (int i = 0; i < 4; ++i) v[i] = (base + i < N) ? cnt[base + i] : 0;
    const int tsum = v[0] + v[1] + v[2] + v[3];
    tmp[tid] = tsum;
    __syncthreads();
    int run = tsum;
    for (int off = 1; off < 256; off <<= 1) {
        int t = (tid >= off) ? tmp[tid - off] : 0;
        __syncthreads();
        run += t;
        tmp[tid] = run;
        __syncthreads();
    }
    int s = run - tsum;   // exclusive prefix of this thread within block
#pragma unroll
    for (int i = 0; i < 4; ++i) {
        if (base + i < N) offs[base + i] = s;
        s += v[i];
    }
    if (tid == 255) bsums[blockIdx.x] = run;   // block total
}

// --- phase 2 — single block scans the block sums (nb <= 1024, i.e. N <= 1,048,576)
__global__ __launch_bounds__(1024) void scan_blocks(int* __restrict__ bsums, int nb) {
    __shared__ int tmp[1024];
    const int tid = threadIdx.x;
    const int v = (tid < nb) ? bsums[tid] : 0;
    tmp[tid] = v;
    __syncthreads();
    int run = v;
    for (int off = 1; off < 1024; off <<= 1) {
        int t = (tid >= off) ? tmp[tid - off] : 0;
        __syncthreads();
        run += t;
        tmp[tid] = run;
        __syncthreads();
    }
    if (tid < nb) bsums[tid] = run - v;   // exclusive
}

// --- phase 3 — add block offsets, emit offs and curs, set offs[N]=E
__global__ __launch_bounds__(256) void scan_add(const int* __restrict__ bsums,
                                                int* __restrict__ offs,
                                                int* __restrict__ curs, int N, int E) {
    const int tid = threadIdx.x;
    const int base = blockIdx.x * 1024 + tid * 4;
    const int add = bsums[blockIdx.x];
#pragma unroll
    for (int i = 0; i < 4; ++i) {
        int idx = base + i;
        if (idx < N) {
            int o = offs[idx] + add;
            offs[idx] = o;
            curs[idx] = o;
        }
    }
    if (blockIdx.x == 0 && tid == 0) offs[N] = E;
}

__global__ void scatter_kernel(const int* __restrict__ src, const int* __restrict__ dst,
                               int* __restrict__ curs, int* __restrict__ csr, int E) {
    int stride = gridDim.x * blockDim.x;
    for (int e = blockIdx.x * blockDim.x + threadIdx.x; e < E; e += stride) {
        int d = dst[e];
        int p = atomicAdd(&curs[d], 1);
        csr[p] = src[e];
    }
}

// G[r, c] = dinv[r] * sum_k X[r,k] * W[k,c].   K fixed at 128.
// Block: 256 threads, 64 rows. Thread tile: 4 rows x (COUT/16) cols.
template <int COUT>
__global__ __launch_bounds__(256) void gemm_scale(const float* __restrict__ X,
                                                  const float* __restrict__ W,
                                                  const float* __restrict__ dinv,
                                                  float* __restrict__ G, int N) {
    constexpr int K = 128, BR = 64, KC = 32;
    constexpr int CPT = COUT / 16;   // 8 (COUT=128) or 4 (COUT=64)
    __shared__ float sx[KC][BR];     // x transposed: [k][row]
    __shared__ float sw[KC][COUT];
    const int tid = threadIdx.x;
    const int tx = tid & 15;   // col group
    const int ty = tid >> 4;   // row group (4 rows each)
    const int r0 = blockIdx.x * BR;

    float acc[4][CPT];
#pragma unroll
    for (int i = 0; i < 4; ++i)
#pragma unroll
        for (int j = 0; j < CPT; ++j) acc[i][j] = 0.f;

    const int lr = tid >> 2;          // 0..63: row within tile for staging
    const int lk = (tid & 3) * 8;     // 0,8,16,24: k offset for staging
    const int gr = min(r0 + lr, N - 1);

    for (int kc = 0; kc < K; kc += KC) {
        float4 a = *reinterpret_cast<const float4*>(&X[(size_t)gr * K + kc + lk]);
        float4 b = *reinterpret_cast<const float4*>(&X[(size_t)gr * K + kc + lk + 4]);
        sx[lk + 0][lr] = a.x; sx[lk + 1][lr] = a.y; sx[lk + 2][lr] = a.z; sx[lk + 3][lr] = a.w;
        sx[lk + 4][lr] = b.x; sx[lk + 5][lr] = b.y; sx[lk + 6][lr] = b.z; sx[lk + 7][lr] = b.w;
        constexpr int NF4 = (KC * COUT) / (256 * 4);
#pragma unroll
        for (int q = 0; q < NF4; ++q) {
            int f = tid + q * 256;
            int kk = (f * 4) / COUT;
            int cc = (f * 4) % COUT;
            *reinterpret_cast<float4*>(&sw[kk][cc]) =
                *reinterpret_cast<const float4*>(&W[(size_t)(kc + kk) * COUT + cc]);
        }
        __syncthreads();
#pragma unroll
        for (int k = 0; k < KC; ++k) {
            float xv[4];
#pragma unroll
            for (int i = 0; i < 4; ++i) xv[i] = sx[k][ty * 4 + i];
            float wv[CPT];
#pragma unroll
            for (int j = 0; j < CPT; j += 4)
                *reinterpret_cast<float4*>(&wv[j]) =
                    *reinterpret_cast<float4*>(&sw[k][tx * CPT + j]);
#pragma unroll
            for (int i = 0; i < 4; ++i)
#pragma unroll
                for (int j = 0; j < CPT; ++j) acc[i][j] += xv[i] * wv[j];
        }
        __syncthreads();
    }
#pragma unroll
    for (int i = 0; i < 4; ++i) {
        int r = r0 + ty * 4 + i;
        if (r < N) {
            float di = dinv[r];
#pragma unroll
            for (int j = 0; j < CPT; j += 4) {
                float4 o;
                o.x = acc[i][j + 0] * di;
                o.y = acc[i][j + 1] * di;
                o.z = acc[i][j + 2] * di;
                o.w = acc[i][j + 3] * di;
                *reinterpret_cast<float4*>(&G[(size_t)r * COUT + tx * CPT + j]) = o;
            }
        }
    }
}

// One wave per node. VEC=2 -> C=128 (float2/lane); VEC=1 -> C=64 (float/lane).
template <int VEC, bool RELU>
__global__ __launch_bounds__(256) void agg_kernel(const float* __restrict__ G,
                                                  const int* __restrict__ offs,
                                                  const int* __restrict__ csr,
                                                  const float* __restrict__ dinv,
                                                  const float* __restrict__ bias,
                                                  float* __restrict__ out, int N) {
    int node = (blockIdx.x * blockDim.x + threadIdx.x) >> 6;
    int lane = threadIdx.x & 63;
    if (node >= N) return;
    int e = offs[node];
    const int end = offs[node + 1];
    if constexpr (VEC == 2) {
        const float2* Gp = reinterpret_cast<const float2*>(G);
        float2 s = Gp[(size_t)node * 64 + lane];   // self-loop term
        float ax = s.x, ay = s.y;
        for (; e + 4 <= end; e += 4) {
            int j0 = csr[e], j1 = csr[e + 1], j2 = csr[e + 2], j3 = csr[e + 3];
            float2 v0 = Gp[(size_t)j0 * 64 + lane];
            float2 v1 = Gp[(size_t)j1 * 64 + lane];
            float2 v2 = Gp[(size_t)j2 * 64 + lane];
            float2 v3 = Gp[(size_t)j3 * 64 + lane];
            ax += v0.x + v1.x + v2.x + v3.x;
            ay += v0.y + v1.y + v2.y + v3.y;
        }
        for (; e < end; ++e) {
            int j = csr[e];
            float2 v = Gp[(size_t)j * 64 + lane];
            ax += v.x; ay += v.y;
        }
        float di = dinv[node];
        float ox = ax * di + bias[lane * 2 + 0];
        float oy = ay * di + bias[lane * 2 + 1];
        if (RELU) { ox = fmaxf(ox, 0.f); oy = fmaxf(oy, 0.f); }
        float2* Op = reinterpret_cast<float2*>(out);
        float2 o; o.x = ox; o.y = oy;
        Op[(size_t)node * 64 + lane] = o;
    } else {
        float acc = G[(size_t)node * 64 + lane];   // self-loop term
        for (; e + 4 <= end; e += 4) {
            int j0 = csr[e], j1 = csr[e + 1], j2 = csr[e + 2], j3 = csr[e + 3];
            float v0 = G[(size_t)j0 * 64 + lane];
            float v1 = G[(size_t)j1 * 64 + lane];
            float v2 = G[(size_t)j2 * 64 + lane];
            float v3 = G[(size_t)j3 * 64 + lane];
            acc += v0 + v1 + v2 + v3;
        }
        for (; e < end; ++e) acc += G[(size_t)csr[e] * 64 + lane];
        float o = acc * dinv[node] + bias[lane];
        if (RELU) o = fmaxf(o, 0.f);
        out[(size_t)node * 64 + lane] = o;
    }
}

extern "C" void kernel_launch(void* const* d_in, const int* in_sizes, int n_in,
                              void* d_out, int out_size, void* d_ws, size_t ws_size,
                              hipStream_t stream) {
    const float* x  = (const float*)d_in[0];
    const int*   ei = (const int*)d_in[1];    // harness delivers integer inputs as int32
    const float* W1 = (const float*)d_in[2];
    const float* b1 = (const float*)d_in[3];
    const float* W2 = (const float*)d_in[4];
    const float* b2 = (const float*)d_in[5];
    float* out = (float*)d_out;

    const int N = in_sizes[0] / 128;
    const int E = in_sizes[1] / 2;
    const int* src = ei;
    const int* dst = ei + E;

    // Workspace layout
    float* g1 = (float*)d_ws;                       // N*128 f32 (51.2 MB); later reused as g2 (N*64)
    float* a1 = g1 + (size_t)N * 128;               // N*128 f32 (51.2 MB)
    float* g2 = g1;
    char* p = (char*)(a1 + (size_t)N * 128);
    int* cnt = (int*)p;    p += (((size_t)N * 4) + 15) & ~(size_t)15;
    float* dinv = (float*)p; p += (((size_t)N * 4) + 15) & ~(size_t)15;
    int* offs = (int*)p;   p += (((size_t)(N + 1) * 4) + 15) & ~(size_t)15;
    int* curs = (int*)p;   p += (((size_t)N * 4) + 15) & ~(size_t)15;
    int* csr = (int*)p;    p += (((size_t)E * 4) + 15) & ~(size_t)15;
    const int nscan = (N + 1023) / 1024;            // blocks in phase-1 scan
    int* bsums = (int*)p;  p += (((size_t)nscan * 4) + 15) & ~(size_t)15;
    if ((size_t)(p - (char*)d_ws) > ws_size) return;  // workspace too small: fail loudly

    // --- graph preprocessing (once, shared by both layers) ---
    zero_i32<<<(N + 255) / 256, 256, 0, stream>>>(cnt, N);
    hist_kernel<<<2048, 256, 0, stream>>>(dst, cnt, E);
    dinv_kernel<<<(N + 255) / 256, 256, 0, stream>>>(cnt, dinv, N);
    scan_local<<<nscan, 256, 0, stream>>>(cnt, offs, bsums, N);
    scan_blocks<<<1, 1024, 0, stream>>>(bsums, nscan);
    scan_add<<<nscan, 256, 0, stream>>>(bsums, offs, curs, N, E);
    scatter_kernel<<<2048, 256, 0, stream>>>(src, dst, curs, csr, E);

    // --- layer 1 ---
    gemm_scale<128><<<(N + 63) / 64, 256, 0, stream>>>(x, W1, dinv, g1, N);
    agg_kernel<2, true><<<(N + 3) / 4, 256, 0, stream>>>(g1, offs, csr, dinv, b1, a1, N);

    // --- layer 2 ---
    gemm_scale<64><<<(N + 63) / 64, 256, 0, stream>>>(a1, W2, dinv, g2, N);
    agg_kernel<1, false><<<(N + 3) / 4, 256, 0, stream>>>(g2, offs, csr, dinv, b2, out, N);
}

// Round 3
// 460.547 us; speedup vs baseline: 1.3436x; 1.0351x over previous
//
#include <hip/hip_runtime.h>
#include <hip/hip_bf16.h>

// ---------------------------------------------------------------------------
// 2-layer GCN. Refactor: g[j] = dinv[j]*(X@W)[j]; out[i] = dinv[i]*(g[i]+sum g[j]) + b
// CSR-by-destination built once, reused by both layers.
// R1: hierarchical scan (160us -> ~8us).
// R2: two-pass bucketed CSR scatter — kills 107MB write-thrash (130us -> ~40us).
// ---------------------------------------------------------------------------

__global__ void zero_i32(int* __restrict__ p, int n) {
    int i = blockIdx.x * blockDim.x + threadIdx.x;
    if (i < n) p[i] = 0;
}

__global__ void hist_kernel(const int* __restrict__ dst, int* __restrict__ cnt, int E) {
    int stride = gridDim.x * blockDim.x;
    for (int e = blockIdx.x * blockDim.x + threadIdx.x; e < E; e += stride)
        atomicAdd(&cnt[dst[e]], 1);
}

__global__ void dinv_kernel(const int* __restrict__ cnt, float* __restrict__ dinv, int N) {
    int i = blockIdx.x * blockDim.x + threadIdx.x;
    if (i < N) dinv[i] = rsqrtf((float)(cnt[i] + 1));   // +1 = self-loop
}

// --- hierarchical scan over cnt -> offs (exclusive), phase 1
__global__ __launch_bounds__(256) void scan_local(const int* __restrict__ cnt,
                                                  int* __restrict__ offs,
                                                  int* __restrict__ bsums, int N) {
    __shared__ int tmp[256];
    const int tid = threadIdx.x;
    const int base = blockIdx.x * 1024 + tid * 4;
    int v[4];
#pragma unroll
    for (int i = 0; i < 4; ++i) v[i] = (base + i < N) ? cnt[base + i] : 0;
    const int tsum = v[0] + v[1] + v[2] + v[3];
    tmp[tid] = tsum;
    __syncthreads();
    int run = tsum;
    for (int off = 1; off < 256; off <<= 1) {
        int t = (tid >= off) ? tmp[tid - off] : 0;
        __syncthreads();
        run += t;
        tmp[tid] = run;
        __syncthreads();
    }
    int s = run - tsum;
#pragma unroll
    for (int i = 0; i < 4; ++i) {
        if (base + i < N) offs[base + i] = s;
        s += v[i];
    }
    if (tid == 255) bsums[blockIdx.x] = run;
}

__global__ __launch_bounds__(1024) void scan_blocks(int* __restrict__ bsums, int nb) {
    __shared__ int tmp[1024];
    const int tid = threadIdx.x;
    const int v = (tid < nb) ? bsums[tid] : 0;
    tmp[tid] = v;
    __syncthreads();
    int run = v;
    for (int off = 1; off < 1024; off <<= 1) {
        int t = (tid >= off) ? tmp[tid - off] : 0;
        __syncthreads();
        run += t;
        tmp[tid] = run;
        __syncthreads();
    }
    if (tid < nb) bsums[tid] = run - v;
}

__global__ __launch_bounds__(256) void scan_add(const int* __restrict__ bsums,
                                                int* __restrict__ offs,
                                                int* __restrict__ curs, int N, int E) {
    const int tid = threadIdx.x;
    const int base = blockIdx.x * 1024 + tid * 4;
    const int add = bsums[blockIdx.x];
#pragma unroll
    for (int i = 0; i < 4; ++i) {
        int idx = base + i;
        if (idx < N) {
            int o = offs[idx] + add;
            offs[idx] = o;
            curs[idx] = o;
        }
    }
    if (blockIdx.x == 0 && tid == 0) offs[N] = E;
}

// --- R2: bucket edges by dst>>10 for L2-local CSR scatter ---
__global__ void bucket_hist(const int* __restrict__ dst, int* __restrict__ bcnt, int E, int nb) {
    __shared__ int h[256];
    for (int t = threadIdx.x; t < nb; t += blockDim.x) h[t] = 0;
    __syncthreads();
    int stride = gridDim.x * blockDim.x;
    for (int e = blockIdx.x * blockDim.x + threadIdx.x; e < E; e += stride)
        atomicAdd(&h[dst[e] >> 10], 1);
    __syncthreads();
    for (int t = threadIdx.x; t < nb; t += blockDim.x)
        if (h[t]) atomicAdd(&bcnt[t], h[t]);
}

__global__ __launch_bounds__(256) void bucket_scan(const int* __restrict__ bcnt,
                                                   int* __restrict__ bcur, int nb) {
    __shared__ int tmp[256];
    const int tid = threadIdx.x;
    const int v = (tid < nb) ? bcnt[tid] : 0;
    tmp[tid] = v;
    __syncthreads();
    int run = v;
    for (int off = 1; off < 256; off <<= 1) {
        int t = (tid >= off) ? tmp[tid - off] : 0;
        __syncthreads();
        run += t;
        tmp[tid] = run;
        __syncthreads();
    }
    if (tid < nb) bcur[tid] = run - v;   // exclusive base; consumed as running cursor
}

// Each block partitions one 4096-edge chunk into buckets with contiguous-run writes.
__global__ __launch_bounds__(256) void partition_kernel(const int* __restrict__ src,
                                                        const int* __restrict__ dst,
                                                        int* __restrict__ bcur,
                                                        int2* __restrict__ ebuf,
                                                        int E, int nb) {
    __shared__ int hist[256];
    __shared__ int basel[256];
    const int tid = threadIdx.x;
    const int c0 = blockIdx.x * 4096;
    for (int t = tid; t < nb; t += 256) hist[t] = 0;
    __syncthreads();
    int s[16], d[16], r[16];
#pragma unroll
    for (int i = 0; i < 16; ++i) {
        int idx = c0 + i * 256 + tid;
        if (idx < E) {
            s[i] = src[idx];
            d[i] = dst[idx];
            r[i] = atomicAdd(&hist[d[i] >> 10], 1);
        } else {
            d[i] = -1;
        }
    }
    __syncthreads();
    for (int t = tid; t < nb; t += 256) basel[t] = hist[t] ? atomicAdd(&bcur[t], hist[t]) : 0;
    __syncthreads();
#pragma unroll
    for (int i = 0; i < 16; ++i) {
        if (d[i] >= 0) {
            int b = d[i] >> 10;
            ebuf[basel[b] + r[i]] = make_int2(s[i], d[i]);
        }
    }
}

// Scatter from bucketed edges: curs atomics + csr stores confined to small hot windows.
__global__ void scatter_bucketed(const int2* __restrict__ ebuf, int* __restrict__ curs,
                                 int* __restrict__ csr, int E) {
    int stride = gridDim.x * blockDim.x;
    for (int e = blockIdx.x * blockDim.x + threadIdx.x; e < E; e += stride) {
        int2 p = ebuf[e];
        int pos = atomicAdd(&curs[p.y], 1);
        csr[pos] = p.x;
    }
}

// G[r, c] = dinv[r] * sum_k X[r,k] * W[k,c].   K fixed at 128.
template <int COUT>
__global__ __launch_bounds__(256) void gemm_scale(const float* __restrict__ X,
                                                  const float* __restrict__ W,
                                                  const float* __restrict__ dinv,
                                                  float* __restrict__ G, int N) {
    constexpr int K = 128, BR = 64, KC = 32;
    constexpr int CPT = COUT / 16;
    __shared__ float sx[KC][BR];
    __shared__ float sw[KC][COUT];
    const int tid = threadIdx.x;
    const int tx = tid & 15;
    const int ty = tid >> 4;
    const int r0 = blockIdx.x * BR;

    float acc[4][CPT];
#pragma unroll
    for (int i = 0; i < 4; ++i)
#pragma unroll
        for (int j = 0; j < CPT; ++j) acc[i][j] = 0.f;

    const int lr = tid >> 2;
    const int lk = (tid & 3) * 8;
    const int gr = min(r0 + lr, N - 1);

    for (int kc = 0; kc < K; kc += KC) {
        float4 a = *reinterpret_cast<const float4*>(&X[(size_t)gr * K + kc + lk]);
        float4 b = *reinterpret_cast<const float4*>(&X[(size_t)gr * K + kc + lk + 4]);
        sx[lk + 0][lr] = a.x; sx[lk + 1][lr] = a.y; sx[lk + 2][lr] = a.z; sx[lk + 3][lr] = a.w;
        sx[lk + 4][lr] = b.x; sx[lk + 5][lr] = b.y; sx[lk + 6][lr] = b.z; sx[lk + 7][lr] = b.w;
        constexpr int NF4 = (KC * COUT) / (256 * 4);
#pragma unroll
        for (int q = 0; q < NF4; ++q) {
            int f = tid + q * 256;
            int kk = (f * 4) / COUT;
            int cc = (f * 4) % COUT;
            *reinterpret_cast<float4*>(&sw[kk][cc]) =
                *reinterpret_cast<const float4*>(&W[(size_t)(kc + kk) * COUT + cc]);
        }
        __syncthreads();
#pragma unroll
        for (int k = 0; k < KC; ++k) {
            float xv[4];
#pragma unroll
            for (int i = 0; i < 4; ++i) xv[i] = sx[k][ty * 4 + i];
            float wv[CPT];
#pragma unroll
            for (int j = 0; j < CPT; j += 4)
                *reinterpret_cast<float4*>(&wv[j]) =
                    *reinterpret_cast<float4*>(&sw[k][tx * CPT + j]);
#pragma unroll
            for (int i = 0; i < 4; ++i)
#pragma unroll
                for (int j = 0; j < CPT; ++j) acc[i][j] += xv[i] * wv[j];
        }
        __syncthreads();
    }
#pragma unroll
    for (int i = 0; i < 4; ++i) {
        int r = r0 + ty * 4 + i;
        if (r < N) {
            float di = dinv[r];
#pragma unroll
            for (int j = 0; j < CPT; j += 4) {
                float4 o;
                o.x = acc[i][j + 0] * di;
                o.y = acc[i][j + 1] * di;
                o.z = acc[i][j + 2] * di;
                o.w = acc[i][j + 3] * di;
                *reinterpret_cast<float4*>(&G[(size_t)r * COUT + tx * CPT + j]) = o;
            }
        }
    }
}

// One wave per node. VEC=2 -> C=128 (float2/lane); VEC=1 -> C=64 (float/lane).
template <int VEC, bool RELU>
__global__ __launch_bounds__(256) void agg_kernel(const float* __restrict__ G,
                                                  const int* __restrict__ offs,
                                                  const int* __restrict__ csr,
                                                  const float* __restrict__ dinv,
                                                  const float* __restrict__ bias,
                                                  float* __restrict__ out, int N) {
    int node = (blockIdx.x * blockDim.x + threadIdx.x) >> 6;
    int lane = threadIdx.x & 63;
    if (node >= N) return;
    int e = offs[node];
    const int end = offs[node + 1];
    if constexpr (VEC == 2) {
        const float2* Gp = reinterpret_cast<const float2*>(G);
        float2 s = Gp[(size_t)node * 64 + lane];
        float ax = s.x, ay = s.y;
        for (; e + 4 <= end; e += 4) {
            int j0 = csr[e], j1 = csr[e + 1], j2 = csr[e + 2], j3 = csr[e + 3];
            float2 v0 = Gp[(size_t)j0 * 64 + lane];
            float2 v1 = Gp[(size_t)j1 * 64 + lane];
            float2 v2 = Gp[(size_t)j2 * 64 + lane];
            float2 v3 = Gp[(size_t)j3 * 64 + lane];
            ax += v0.x + v1.x + v2.x + v3.x;
            ay += v0.y + v1.y + v2.y + v3.y;
        }
        for (; e < end; ++e) {
            int j = csr[e];
            float2 v = Gp[(size_t)j * 64 + lane];
            ax += v.x; ay += v.y;
        }
        float di = dinv[node];
        float ox = ax * di + bias[lane * 2 + 0];
        float oy = ay * di + bias[lane * 2 + 1];
        if (RELU) { ox = fmaxf(ox, 0.f); oy = fmaxf(oy, 0.f); }
        float2* Op = reinterpret_cast<float2*>(out);
        float2 o; o.x = ox; o.y = oy;
        Op[(size_t)node * 64 + lane] = o;
    } else {
        float acc = G[(size_t)node * 64 + lane];
        for (; e + 4 <= end; e += 4) {
            int j0 = csr[e], j1 = csr[e + 1], j2 = csr[e + 2], j3 = csr[e + 3];
            float v0 = G[(size_t)j0 * 64 + lane];
            float v1 = G[(size_t)j1 * 64 + lane];
            float v2 = G[(size_t)j2 * 64 + lane];
            float v3 = G[(size_t)j3 * 64 + lane];
            acc += v0 + v1 + v2 + v3;
        }
        for (; e < end; ++e) acc += G[(size_t)csr[e] * 64 + lane];
        float o = acc * dinv[node] + bias[lane];
        if (RELU) o = fmaxf(o, 0.f);
        out[(size_t)node * 64 + lane] = o;
    }
}

extern "C" void kernel_launch(void* const* d_in, const int* in_sizes, int n_in,
                              void* d_out, int out_size, void* d_ws, size_t ws_size,
                              hipStream_t stream) {
    const float* x  = (const float*)d_in[0];
    const int*   ei = (const int*)d_in[1];
    const float* W1 = (const float*)d_in[2];
    const float* b1 = (const float*)d_in[3];
    const float* W2 = (const float*)d_in[4];
    const float* b2 = (const float*)d_in[5];
    float* out = (float*)d_out;

    const int N = in_sizes[0] / 128;
    const int E = in_sizes[1] / 2;
    const int* src = ei;
    const int* dst = ei + E;
    const int nbkt = (N + 1023) >> 10;   // dst>>10 buckets; must be <= 256

    // Workspace layout
    float* g1 = (float*)d_ws;                       // N*128 f32; later reused as g2 (N*64)
    float* a1 = g1 + (size_t)N * 128;               // N*128 f32
    float* g2 = g1;
    int2* ebuf = (int2*)d_ws;                       // E*8B, aliases g1 (lifetime-disjoint:
                                                    // ebuf dead before gemm1 writes g1)
    char* p = (char*)(a1 + (size_t)N * 128);
    int* cnt = (int*)p;    p += (((size_t)N * 4) + 15) & ~(size_t)15;
    float* dinv = (float*)p; p += (((size_t)N * 4) + 15) & ~(size_t)15;
    int* offs = (int*)p;   p += (((size_t)(N + 1) * 4) + 15) & ~(size_t)15;
    int* curs = (int*)p;   p += (((size_t)N * 4) + 15) & ~(size_t)15;
    int* csr = (int*)p;    p += (((size_t)E * 4) + 15) & ~(size_t)15;
    const int nscan = (N + 1023) / 1024;
    int* bsums = (int*)p;  p += (((size_t)nscan * 4) + 15) & ~(size_t)15;
    int* bcnt = (int*)p;   p += (((size_t)256 * 4) + 15) & ~(size_t)15;
    int* bcur = (int*)p;   p += (((size_t)256 * 4) + 15) & ~(size_t)15;
    if ((size_t)(p - (char*)d_ws) > ws_size || nbkt > 256 ||
        (size_t)E * 8 > (size_t)N * 128 * 4) return;  // fail loudly

    // --- graph preprocessing (once, shared by both layers) ---
    zero_i32<<<(N + 255) / 256, 256, 0, stream>>>(cnt, N);
    zero_i32<<<1, 256, 0, stream>>>(bcnt, 256);
    hist_kernel<<<2048, 256, 0, stream>>>(dst, cnt, E);
    dinv_kernel<<<(N + 255) / 256, 256, 0, stream>>>(cnt, dinv, N);
    scan_local<<<nscan, 256, 0, stream>>>(cnt, offs, bsums, N);
    scan_blocks<<<1, 1024, 0, stream>>>(bsums, nscan);
    scan_add<<<nscan, 256, 0, stream>>>(bsums, offs, curs, N, E);
    bucket_hist<<<1024, 256, 0, stream>>>(dst, bcnt, E, nbkt);
    bucket_scan<<<1, 256, 0, stream>>>(bcnt, bcur, nbkt);
    partition_kernel<<<(E + 4095) / 4096, 256, 0, stream>>>(src, dst, bcur, ebuf, E, nbkt);
    scatter_bucketed<<<2048, 256, 0, stream>>>(ebuf, curs, csr, E);

    // --- layer 1 ---
    gemm_scale<128><<<(N + 63) / 64, 256, 0, stream>>>(x, W1, dinv, g1, N);
    agg_kernel<2, true><<<(N + 3) / 4, 256, 0, stream>>>(g1, offs, csr, dinv, b1, a1, N);

    // --- layer 2 ---
    gemm_scale<64><<<(N + 63) / 64, 256, 0, stream>>>(a1, W2, dinv, g2, N);
    agg_kernel<1, false><<<(N + 3) / 4, 256, 0, stream>>>(g2, offs, csr, dinv, b2, out, N);
}

// Round 4
// 400.392 us; speedup vs baseline: 1.5454x; 1.1502x over previous
//
#include <hip/hip_runtime.h>
#include <hip/hip_bf16.h>

// ---------------------------------------------------------------------------
// 2-layer GCN. g[j] = dinv[j]*(X@W)[j] stored BF16; out[i] = dinv[i]*(g[i]+sum g[j]) + b
// CSR-by-destination built once, reused by both layers.
// R1: hierarchical scan (160us -> ~8us).
// R2: bucketed CSR scatter — kills 107MB write-thrash (130us -> ~40us).
// R3: bf16 gather tables — halves edge-gather bytes (agg1 118us -> ~65us).
// ---------------------------------------------------------------------------

__device__ __forceinline__ unsigned pack_bf16_2(float a, float b) {
    unsigned ua = __builtin_bit_cast(unsigned, a);
    unsigned ub = __builtin_bit_cast(unsigned, b);
    ua += 0x7FFFu + ((ua >> 16) & 1u);   // RNE to bf16
    ub += 0x7FFFu + ((ub >> 16) & 1u);
    return (ua >> 16) | (ub & 0xFFFF0000u);
}
__device__ __forceinline__ float bf16_lo(unsigned v) {
    return __builtin_bit_cast(float, v << 16);
}
__device__ __forceinline__ float bf16_hi(unsigned v) {
    return __builtin_bit_cast(float, v & 0xFFFF0000u);
}

__global__ void zero_i32(int* __restrict__ p, int n) {
    int i = blockIdx.x * blockDim.x + threadIdx.x;
    if (i < n) p[i] = 0;
}

__global__ void hist_kernel(const int* __restrict__ dst, int* __restrict__ cnt, int E) {
    int stride = gridDim.x * blockDim.x;
    for (int e = blockIdx.x * blockDim.x + threadIdx.x; e < E; e += stride)
        atomicAdd(&cnt[dst[e]], 1);
}

__global__ void dinv_kernel(const int* __restrict__ cnt, float* __restrict__ dinv, int N) {
    int i = blockIdx.x * blockDim.x + threadIdx.x;
    if (i < N) dinv[i] = rsqrtf((float)(cnt[i] + 1));   // +1 = self-loop
}

// --- hierarchical scan over cnt -> offs (exclusive)
__global__ __launch_bounds__(256) void scan_local(const int* __restrict__ cnt,
                                                  int* __restrict__ offs,
                                                  int* __restrict__ bsums, int N) {
    __shared__ int tmp[256];
    const int tid = threadIdx.x;
    const int base = blockIdx.x * 1024 + tid * 4;
    int v[4];
#pragma unroll
    for (int i = 0; i < 4; ++i) v[i] = (base + i < N) ? cnt[base + i] : 0;
    const int tsum = v[0] + v[1] + v[2] + v[3];
    tmp[tid] = tsum;
    __syncthreads();
    int run = tsum;
    for (int off = 1; off < 256; off <<= 1) {
        int t = (tid >= off) ? tmp[tid - off] : 0;
        __syncthreads();
        run += t;
        tmp[tid] = run;
        __syncthreads();
    }
    int s = run - tsum;
#pragma unroll
    for (int i = 0; i < 4; ++i) {
        if (base + i < N) offs[base + i] = s;
        s += v[i];
    }
    if (tid == 255) bsums[blockIdx.x] = run;
}

__global__ __launch_bounds__(1024) void scan_blocks(int* __restrict__ bsums, int nb) {
    __shared__ int tmp[1024];
    const int tid = threadIdx.x;
    const int v = (tid < nb) ? bsums[tid] : 0;
    tmp[tid] = v;
    __syncthreads();
    int run = v;
    for (int off = 1; off < 1024; off <<= 1) {
        int t = (tid >= off) ? tmp[tid - off] : 0;
        __syncthreads();
        run += t;
        tmp[tid] = run;
        __syncthreads();
    }
    if (tid < nb) bsums[tid] = run - v;
}

__global__ __launch_bounds__(256) void scan_add(const int* __restrict__ bsums,
                                                int* __restrict__ offs,
                                                int* __restrict__ curs, int N, int E) {
    const int tid = threadIdx.x;
    const int base = blockIdx.x * 1024 + tid * 4;
    const int add = bsums[blockIdx.x];
#pragma unroll
    for (int i = 0; i < 4; ++i) {
        int idx = base + i;
        if (idx < N) {
            int o = offs[idx] + add;
            offs[idx] = o;
            curs[idx] = o;
        }
    }
    if (blockIdx.x == 0 && tid == 0) offs[N] = E;
}

// --- bucketed CSR scatter (R2) ---
__global__ void bucket_hist(const int* __restrict__ dst, int* __restrict__ bcnt, int E, int nb) {
    __shared__ int h[256];
    for (int t = threadIdx.x; t < nb; t += blockDim.x) h[t] = 0;
    __syncthreads();
    int stride = gridDim.x * blockDim.x;
    for (int e = blockIdx.x * blockDim.x + threadIdx.x; e < E; e += stride)
        atomicAdd(&h[dst[e] >> 10], 1);
    __syncthreads();
    for (int t = threadIdx.x; t < nb; t += blockDim.x)
        if (h[t]) atomicAdd(&bcnt[t], h[t]);
}

__global__ __launch_bounds__(256) void bucket_scan(const int* __restrict__ bcnt,
                                                   int* __restrict__ bcur, int nb) {
    __shared__ int tmp[256];
    const int tid = threadIdx.x;
    const int v = (tid < nb) ? bcnt[tid] : 0;
    tmp[tid] = v;
    __syncthreads();
    int run = v;
    for (int off = 1; off < 256; off <<= 1) {
        int t = (tid >= off) ? tmp[tid - off] : 0;
        __syncthreads();
        run += t;
        tmp[tid] = run;
        __syncthreads();
    }
    if (tid < nb) bcur[tid] = run - v;
}

__global__ __launch_bounds__(256) void partition_kernel(const int* __restrict__ src,
                                                        const int* __restrict__ dst,
                                                        int* __restrict__ bcur,
                                                        int2* __restrict__ ebuf,
                                                        int E, int nb) {
    __shared__ int hist[256];
    __shared__ int basel[256];
    const int tid = threadIdx.x;
    const int c0 = blockIdx.x * 4096;
    for (int t = tid; t < nb; t += 256) hist[t] = 0;
    __syncthreads();
    int s[16], d[16], r[16];
#pragma unroll
    for (int i = 0; i < 16; ++i) {
        int idx = c0 + i * 256 + tid;
        if (idx < E) {
            s[i] = src[idx];
            d[i] = dst[idx];
            r[i] = atomicAdd(&hist[d[i] >> 10], 1);
        } else {
            d[i] = -1;
        }
    }
    __syncthreads();
    for (int t = tid; t < nb; t += 256) basel[t] = hist[t] ? atomicAdd(&bcur[t], hist[t]) : 0;
    __syncthreads();
#pragma unroll
    for (int i = 0; i < 16; ++i) {
        if (d[i] >= 0) {
            int b = d[i] >> 10;
            ebuf[basel[b] + r[i]] = make_int2(s[i], d[i]);
        }
    }
}

__global__ void scatter_bucketed(const int2* __restrict__ ebuf, int* __restrict__ curs,
                                 int* __restrict__ csr, int E) {
    int stride = gridDim.x * blockDim.x;
    for (int e = blockIdx.x * blockDim.x + threadIdx.x; e < E; e += stride) {
        int2 p = ebuf[e];
        int pos = atomicAdd(&curs[p.y], 1);
        csr[pos] = p.x;
    }
}

// G[r,c] = bf16( dinv[r] * sum_k X[r,k]*W[k,c] ).  K fixed at 128. Output packed 2/uint.
template <int COUT>
__global__ __launch_bounds__(256) void gemm_scale(const float* __restrict__ X,
                                                  const float* __restrict__ W,
                                                  const float* __restrict__ dinv,
                                                  unsigned* __restrict__ Gb, int N) {
    constexpr int K = 128, BR = 64, KC = 32;
    constexpr int CPT = COUT / 16;
    __shared__ float sx[KC][BR];
    __shared__ float sw[KC][COUT];
    const int tid = threadIdx.x;
    const int tx = tid & 15;
    const int ty = tid >> 4;
    const int r0 = blockIdx.x * BR;

    float acc[4][CPT];
#pragma unroll
    for (int i = 0; i < 4; ++i)
#pragma unroll
        for (int j = 0; j < CPT; ++j) acc[i][j] = 0.f;

    const int lr = tid >> 2;
    const int lk = (tid & 3) * 8;
    const int gr = min(r0 + lr, N - 1);

    for (int kc = 0; kc < K; kc += KC) {
        float4 a = *reinterpret_cast<const float4*>(&X[(size_t)gr * K + kc + lk]);
        float4 b = *reinterpret_cast<const float4*>(&X[(size_t)gr * K + kc + lk + 4]);
        sx[lk + 0][lr] = a.x; sx[lk + 1][lr] = a.y; sx[lk + 2][lr] = a.z; sx[lk + 3][lr] = a.w;
        sx[lk + 4][lr] = b.x; sx[lk + 5][lr] = b.y; sx[lk + 6][lr] = b.z; sx[lk + 7][lr] = b.w;
        constexpr int NF4 = (KC * COUT) / (256 * 4);
#pragma unroll
        for (int q = 0; q < NF4; ++q) {
            int f = tid + q * 256;
            int kk = (f * 4) / COUT;
            int cc = (f * 4) % COUT;
            *reinterpret_cast<float4*>(&sw[kk][cc]) =
                *reinterpret_cast<const float4*>(&W[(size_t)(kc + kk) * COUT + cc]);
        }
        __syncthreads();
#pragma unroll
        for (int k = 0; k < KC; ++k) {
            float xv[4];
#pragma unroll
            for (int i = 0; i < 4; ++i) xv[i] = sx[k][ty * 4 + i];
            float wv[CPT];
#pragma unroll
            for (int j = 0; j < CPT; j += 4)
                *reinterpret_cast<float4*>(&wv[j]) =
                    *reinterpret_cast<float4*>(&sw[k][tx * CPT + j]);
#pragma unroll
            for (int i = 0; i < 4; ++i)
#pragma unroll
                for (int j = 0; j < CPT; ++j) acc[i][j] += xv[i] * wv[j];
        }
        __syncthreads();
    }
#pragma unroll
    for (int i = 0; i < 4; ++i) {
        int r = r0 + ty * 4 + i;
        if (r < N) {
            float di = dinv[r];
#pragma unroll
            for (int j = 0; j < CPT; j += 4) {
                uint2 o;
                o.x = pack_bf16_2(acc[i][j + 0] * di, acc[i][j + 1] * di);
                o.y = pack_bf16_2(acc[i][j + 2] * di, acc[i][j + 3] * di);
                *reinterpret_cast<uint2*>(&Gb[(size_t)r * (COUT / 2) + (tx * CPT + j) / 2]) = o;
            }
        }
    }
}

// Layer-1 aggregate: 128 bf16 cols/row, one wave per node, lane covers cols {2l, 2l+1}.
__global__ __launch_bounds__(256) void agg1_kernel(const unsigned* __restrict__ Gb,
                                                   const int* __restrict__ offs,
                                                   const int* __restrict__ csr,
                                                   const float* __restrict__ dinv,
                                                   const float* __restrict__ bias,
                                                   float* __restrict__ out, int N) {
    int node = (blockIdx.x * blockDim.x + threadIdx.x) >> 6;
    int lane = threadIdx.x & 63;
    if (node >= N) return;
    int e = offs[node];
    const int end = offs[node + 1];
    unsigned sv = Gb[(size_t)node * 64 + lane];          // self-loop term
    float ax = bf16_lo(sv), ay = bf16_hi(sv);
    for (; e + 4 <= end; e += 4) {
        int j0 = csr[e], j1 = csr[e + 1], j2 = csr[e + 2], j3 = csr[e + 3];
        unsigned v0 = Gb[(size_t)j0 * 64 + lane];
        unsigned v1 = Gb[(size_t)j1 * 64 + lane];
        unsigned v2 = Gb[(size_t)j2 * 64 + lane];
        unsigned v3 = Gb[(size_t)j3 * 64 + lane];
        ax += bf16_lo(v0) + bf16_lo(v1) + bf16_lo(v2) + bf16_lo(v3);
        ay += bf16_hi(v0) + bf16_hi(v1) + bf16_hi(v2) + bf16_hi(v3);
    }
    for (; e < end; ++e) {
        unsigned v = Gb[(size_t)csr[e] * 64 + lane];
        ax += bf16_lo(v); ay += bf16_hi(v);
    }
    float di = dinv[node];
    float2 o;
    o.x = fmaxf(ax * di + bias[lane * 2 + 0], 0.f);      // ReLU
    o.y = fmaxf(ay * di + bias[lane * 2 + 1], 0.f);
    *reinterpret_cast<float2*>(&out[(size_t)node * 128 + lane * 2]) = o;
}

// Layer-2 aggregate: 64 bf16 cols/row = 32 uints; two nodes per wave (half-wave each).
__global__ __launch_bounds__(256) void agg2_kernel(const unsigned* __restrict__ Gb,
                                                   const int* __restrict__ offs,
                                                   const int* __restrict__ csr,
                                                   const float* __restrict__ dinv,
                                                   const float* __restrict__ bias,
                                                   float* __restrict__ out, int N) {
    int tid = blockIdx.x * blockDim.x + threadIdx.x;
    int node = (tid >> 6) * 2 + ((threadIdx.x >> 5) & 1);
    int c = threadIdx.x & 31;                            // uint column
    if (node >= N) return;
    int e = offs[node];
    const int end = offs[node + 1];
    unsigned sv = Gb[(size_t)node * 32 + c];
    float ax = bf16_lo(sv), ay = bf16_hi(sv);
    for (; e + 4 <= end; e += 4) {
        int j0 = csr[e], j1 = csr[e + 1], j2 = csr[e + 2], j3 = csr[e + 3];
        unsigned v0 = Gb[(size_t)j0 * 32 + c];
        unsigned v1 = Gb[(size_t)j1 * 32 + c];
        unsigned v2 = Gb[(size_t)j2 * 32 + c];
        unsigned v3 = Gb[(size_t)j3 * 32 + c];
        ax += bf16_lo(v0) + bf16_lo(v1) + bf16_lo(v2) + bf16_lo(v3);
        ay += bf16_hi(v0) + bf16_hi(v1) + bf16_hi(v2) + bf16_hi(v3);
    }
    for (; e < end; ++e) {
        unsigned v = Gb[(size_t)csr[e] * 32 + c];
        ax += bf16_lo(v); ay += bf16_hi(v);
    }
    float di = dinv[node];
    float2 o;
    o.x = ax * di + bias[c * 2 + 0];
    o.y = ay * di + bias[c * 2 + 1];
    *reinterpret_cast<float2*>(&out[(size_t)node * 64 + c * 2]) = o;
}

extern "C" void kernel_launch(void* const* d_in, const int* in_sizes, int n_in,
                              void* d_out, int out_size, void* d_ws, size_t ws_size,
                              hipStream_t stream) {
    const float* x  = (const float*)d_in[0];
    const int*   ei = (const int*)d_in[1];
    const float* W1 = (const float*)d_in[2];
    const float* b1 = (const float*)d_in[3];
    const float* W2 = (const float*)d_in[4];
    const float* b2 = (const float*)d_in[5];
    float* out = (float*)d_out;

    const int N = in_sizes[0] / 128;
    const int E = in_sizes[1] / 2;
    const int* src = ei;
    const int* dst = ei + E;
    const int nbkt = (N + 1023) >> 10;   // must be <= 256

    // Workspace layout
    unsigned* g1b = (unsigned*)d_ws;                 // N*64 uints (25.6MB) bf16 g1; reused as g2b
    float* a1 = (float*)(g1b + (size_t)N * 64);      // N*128 f32 (51.2MB)
    unsigned* g2b = g1b;                             // N*32 uints, aliases g1b
    int2* ebuf = (int2*)d_ws;                        // E*8B, aliases g1b (lifetime-disjoint)
    char* p = (char*)(a1 + (size_t)N * 128);
    int* cnt = (int*)p;    p += (((size_t)N * 4) + 15) & ~(size_t)15;
    float* dinv = (float*)p; p += (((size_t)N * 4) + 15) & ~(size_t)15;
    int* offs = (int*)p;   p += (((size_t)(N + 1) * 4) + 15) & ~(size_t)15;
    int* curs = (int*)p;   p += (((size_t)N * 4) + 15) & ~(size_t)15;
    int* csr = (int*)p;    p += (((size_t)E * 4) + 15) & ~(size_t)15;
    const int nscan = (N + 1023) / 1024;
    int* bsums = (int*)p;  p += (((size_t)nscan * 4) + 15) & ~(size_t)15;
    int* bcnt = (int*)p;   p += (((size_t)256 * 4) + 15) & ~(size_t)15;
    int* bcur = (int*)p;   p += (((size_t)256 * 4) + 15) & ~(size_t)15;
    if ((size_t)(p - (char*)d_ws) > ws_size || nbkt > 256 ||
        (size_t)E * 8 > (size_t)N * 64 * 4) return;  // fail loudly

    // --- graph preprocessing (once, shared by both layers) ---
    zero_i32<<<(N + 255) / 256, 256, 0, stream>>>(cnt, N);
    zero_i32<<<1, 256, 0, stream>>>(bcnt, 256);
    hist_kernel<<<2048, 256, 0, stream>>>(dst, cnt, E);
    dinv_kernel<<<(N + 255) / 256, 256, 0, stream>>>(cnt, dinv, N);
    scan_local<<<nscan, 256, 0, stream>>>(cnt, offs, bsums, N);
    scan_blocks<<<1, 1024, 0, stream>>>(bsums, nscan);
    scan_add<<<nscan, 256, 0, stream>>>(bsums, offs, curs, N, E);
    bucket_hist<<<1024, 256, 0, stream>>>(dst, bcnt, E, nbkt);
    bucket_scan<<<1, 256, 0, stream>>>(bcnt, bcur, nbkt);
    partition_kernel<<<(E + 4095) / 4096, 256, 0, stream>>>(src, dst, bcur, ebuf, E, nbkt);
    scatter_bucketed<<<2048, 256, 0, stream>>>(ebuf, curs, csr, E);

    // --- layer 1 ---
    gemm_scale<128><<<(N + 63) / 64, 256, 0, stream>>>(x, W1, dinv, g1b, N);
    agg1_kernel<<<(N + 3) / 4, 256, 0, stream>>>(g1b, offs, csr, dinv, b1, a1, N);

    // --- layer 2 ---
    gemm_scale<64><<<(N + 63) / 64, 256, 0, stream>>>(a1, W2, dinv, g2b, N);
    agg2_kernel<<<(N + 7) / 8, 256, 0, stream>>>(g2b, offs, csr, dinv, b2, out, N);
}

// Round 5
// 369.674 us; speedup vs baseline: 1.6739x; 1.0831x over previous
//
#include <hip/hip_runtime.h>
#include <hip/hip_bf16.h>

// ---------------------------------------------------------------------------
// 2-layer GCN. g[j] = dinv[j]*(X@W)[j] stored BF16; out[i] = dinv[i]*(g[i]+sum g[j]) + b
// CSR-by-destination built once, reused by both layers.
// R1: hierarchical scan (160us -> ~8us).
// R2: bucketed CSR scatter — kills 107MB write-thrash (130us -> ~40us).
// R3: bf16 gather tables — halves edge-gather bytes (agg1 118us -> ~65us).
// R5: degree histogram from bucketed ebuf (kills 102MB random-atomic RMW);
//     8-deep gather unroll in agg kernels (latency-bound -> more MLP).
// ---------------------------------------------------------------------------

__device__ __forceinline__ unsigned pack_bf16_2(float a, float b) {
    unsigned ua = __builtin_bit_cast(unsigned, a);
    unsigned ub = __builtin_bit_cast(unsigned, b);
    ua += 0x7FFFu + ((ua >> 16) & 1u);   // RNE to bf16
    ub += 0x7FFFu + ((ub >> 16) & 1u);
    return (ua >> 16) | (ub & 0xFFFF0000u);
}
__device__ __forceinline__ float bf16_lo(unsigned v) {
    return __builtin_bit_cast(float, v << 16);
}
__device__ __forceinline__ float bf16_hi(unsigned v) {
    return __builtin_bit_cast(float, v & 0xFFFF0000u);
}

__global__ void zero_i32(int* __restrict__ p, int n) {
    int i = blockIdx.x * blockDim.x + threadIdx.x;
    if (i < n) p[i] = 0;
}

__global__ void dinv_kernel(const int* __restrict__ cnt, float* __restrict__ dinv, int N) {
    int i = blockIdx.x * blockDim.x + threadIdx.x;
    if (i < N) dinv[i] = rsqrtf((float)(cnt[i] + 1));   // +1 = self-loop
}

// --- hierarchical scan over cnt -> offs (exclusive)
__global__ __launch_bounds__(256) void scan_local(const int* __restrict__ cnt,
                                                  int* __restrict__ offs,
                                                  int* __restrict__ bsums, int N) {
    __shared__ int tmp[256];
    const int tid = threadIdx.x;
    const int base = blockIdx.x * 1024 + tid * 4;
    int v[4];
#pragma unroll
    for (int i = 0; i < 4; ++i) v[i] = (base + i < N) ? cnt[base + i] : 0;
    const int tsum = v[0] + v[1] + v[2] + v[3];
    tmp[tid] = tsum;
    __syncthreads();
    int run = tsum;
    for (int off = 1; off < 256; off <<= 1) {
        int t = (tid >= off) ? tmp[tid - off] : 0;
        __syncthreads();
        run += t;
        tmp[tid] = run;
        __syncthreads();
    }
    int s = run - tsum;
#pragma unroll
    for (int i = 0; i < 4; ++i) {
        if (base + i < N) offs[base + i] = s;
        s += v[i];
    }
    if (tid == 255) bsums[blockIdx.x] = run;
}

__global__ __launch_bounds__(1024) void scan_blocks(int* __restrict__ bsums, int nb) {
    __shared__ int tmp[1024];
    const int tid = threadIdx.x;
    const int v = (tid < nb) ? bsums[tid] : 0;
    tmp[tid] = v;
    __syncthreads();
    int run = v;
    for (int off = 1; off < 1024; off <<= 1) {
        int t = (tid >= off) ? tmp[tid - off] : 0;
        __syncthreads();
        run += t;
        tmp[tid] = run;
        __syncthreads();
    }
    if (tid < nb) bsums[tid] = run - v;
}

__global__ __launch_bounds__(256) void scan_add(const int* __restrict__ bsums,
                                                int* __restrict__ offs,
                                                int* __restrict__ curs, int N, int E) {
    const int tid = threadIdx.x;
    const int base = blockIdx.x * 1024 + tid * 4;
    const int add = bsums[blockIdx.x];
#pragma unroll
    for (int i = 0; i < 4; ++i) {
        int idx = base + i;
        if (idx < N) {
            int o = offs[idx] + add;
            offs[idx] = o;
            curs[idx] = o;
        }
    }
    if (blockIdx.x == 0 && tid == 0) offs[N] = E;
}

// --- bucketed CSR scatter (R2) ---
__global__ void bucket_hist(const int* __restrict__ dst, int* __restrict__ bcnt, int E, int nb) {
    __shared__ int h[256];
    for (int t = threadIdx.x; t < nb; t += blockDim.x) h[t] = 0;
    __syncthreads();
    int stride = gridDim.x * blockDim.x;
    for (int e = blockIdx.x * blockDim.x + threadIdx.x; e < E; e += stride)
        atomicAdd(&h[dst[e] >> 10], 1);
    __syncthreads();
    for (int t = threadIdx.x; t < nb; t += blockDim.x)
        if (h[t]) atomicAdd(&bcnt[t], h[t]);
}

__global__ __launch_bounds__(256) void bucket_scan(const int* __restrict__ bcnt,
                                                   int* __restrict__ bcur, int nb) {
    __shared__ int tmp[256];
    const int tid = threadIdx.x;
    const int v = (tid < nb) ? bcnt[tid] : 0;
    tmp[tid] = v;
    __syncthreads();
    int run = v;
    for (int off = 1; off < 256; off <<= 1) {
        int t = (tid >= off) ? tmp[tid - off] : 0;
        __syncthreads();
        run += t;
        tmp[tid] = run;
        __syncthreads();
    }
    if (tid < nb) bcur[tid] = run - v;
}

__global__ __launch_bounds__(256) void partition_kernel(const int* __restrict__ src,
                                                        const int* __restrict__ dst,
                                                        int* __restrict__ bcur,
                                                        int2* __restrict__ ebuf,
                                                        int E, int nb) {
    __shared__ int hist[256];
    __shared__ int basel[256];
    const int tid = threadIdx.x;
    const int c0 = blockIdx.x * 4096;
    for (int t = tid; t < nb; t += 256) hist[t] = 0;
    __syncthreads();
    int s[16], d[16], r[16];
#pragma unroll
    for (int i = 0; i < 16; ++i) {
        int idx = c0 + i * 256 + tid;
        if (idx < E) {
            s[i] = src[idx];
            d[i] = dst[idx];
            r[i] = atomicAdd(&hist[d[i] >> 10], 1);
        } else {
            d[i] = -1;
        }
    }
    __syncthreads();
    for (int t = tid; t < nb; t += 256) basel[t] = hist[t] ? atomicAdd(&bcur[t], hist[t]) : 0;
    __syncthreads();
#pragma unroll
    for (int i = 0; i < 16; ++i) {
        if (d[i] >= 0) {
            int b = d[i] >> 10;
            ebuf[basel[b] + r[i]] = make_int2(s[i], d[i]);
        }
    }
}

// R5: degree histogram over bucketed edges — atomics land in hot per-bucket windows.
__global__ void hist_bucketed(const int2* __restrict__ ebuf, int* __restrict__ cnt, int E) {
    int stride = gridDim.x * blockDim.x;
    for (int e = blockIdx.x * blockDim.x + threadIdx.x; e < E; e += stride)
        atomicAdd(&cnt[ebuf[e].y], 1);
}

__global__ void scatter_bucketed(const int2* __restrict__ ebuf, int* __restrict__ curs,
                                 int* __restrict__ csr, int E) {
    int stride = gridDim.x * blockDim.x;
    for (int e = blockIdx.x * blockDim.x + threadIdx.x; e < E; e += stride) {
        int2 p = ebuf[e];
        int pos = atomicAdd(&curs[p.y], 1);
        csr[pos] = p.x;
    }
}

// G[r,c] = bf16( dinv[r] * sum_k X[r,k]*W[k,c] ).  K fixed at 128. Output packed 2/uint.
template <int COUT>
__global__ __launch_bounds__(256) void gemm_scale(const float* __restrict__ X,
                                                  const float* __restrict__ W,
                                                  const float* __restrict__ dinv,
                                                  unsigned* __restrict__ Gb, int N) {
    constexpr int K = 128, BR = 64, KC = 32;
    constexpr int CPT = COUT / 16;
    __shared__ float sx[KC][BR];
    __shared__ float sw[KC][COUT];
    const int tid = threadIdx.x;
    const int tx = tid & 15;
    const int ty = tid >> 4;
    const int r0 = blockIdx.x * BR;

    float acc[4][CPT];
#pragma unroll
    for (int i = 0; i < 4; ++i)
#pragma unroll
        for (int j = 0; j < CPT; ++j) acc[i][j] = 0.f;

    const int lr = tid >> 2;
    const int lk = (tid & 3) * 8;
    const int gr = min(r0 + lr, N - 1);

    for (int kc = 0; kc < K; kc += KC) {
        float4 a = *reinterpret_cast<const float4*>(&X[(size_t)gr * K + kc + lk]);
        float4 b = *reinterpret_cast<const float4*>(&X[(size_t)gr * K + kc + lk + 4]);
        sx[lk + 0][lr] = a.x; sx[lk + 1][lr] = a.y; sx[lk + 2][lr] = a.z; sx[lk + 3][lr] = a.w;
        sx[lk + 4][lr] = b.x; sx[lk + 5][lr] = b.y; sx[lk + 6][lr] = b.z; sx[lk + 7][lr] = b.w;
        constexpr int NF4 = (KC * COUT) / (256 * 4);
#pragma unroll
        for (int q = 0; q < NF4; ++q) {
            int f = tid + q * 256;
            int kk = (f * 4) / COUT;
            int cc = (f * 4) % COUT;
            *reinterpret_cast<float4*>(&sw[kk][cc]) =
                *reinterpret_cast<const float4*>(&W[(size_t)(kc + kk) * COUT + cc]);
        }
        __syncthreads();
#pragma unroll
        for (int k = 0; k < KC; ++k) {
            float xv[4];
#pragma unroll
            for (int i = 0; i < 4; ++i) xv[i] = sx[k][ty * 4 + i];
            float wv[CPT];
#pragma unroll
            for (int j = 0; j < CPT; j += 4)
                *reinterpret_cast<float4*>(&wv[j]) =
                    *reinterpret_cast<float4*>(&sw[k][tx * CPT + j]);
#pragma unroll
            for (int i = 0; i < 4; ++i)
#pragma unroll
                for (int j = 0; j < CPT; ++j) acc[i][j] += xv[i] * wv[j];
        }
        __syncthreads();
    }
#pragma unroll
    for (int i = 0; i < 4; ++i) {
        int r = r0 + ty * 4 + i;
        if (r < N) {
            float di = dinv[r];
#pragma unroll
            for (int j = 0; j < CPT; j += 4) {
                uint2 o;
                o.x = pack_bf16_2(acc[i][j + 0] * di, acc[i][j + 1] * di);
                o.y = pack_bf16_2(acc[i][j + 2] * di, acc[i][j + 3] * di);
                *reinterpret_cast<uint2*>(&Gb[(size_t)r * (COUT / 2) + (tx * CPT + j) / 2]) = o;
            }
        }
    }
}

// Layer-1 aggregate: 128 bf16 cols/row, one wave per node, 8-deep gather unroll.
__global__ __launch_bounds__(256) void agg1_kernel(const unsigned* __restrict__ Gb,
                                                   const int* __restrict__ offs,
                                                   const int* __restrict__ csr,
                                                   const float* __restrict__ dinv,
                                                   const float* __restrict__ bias,
                                                   float* __restrict__ out, int N) {
    int node = (blockIdx.x * blockDim.x + threadIdx.x) >> 6;
    int lane = threadIdx.x & 63;
    if (node >= N) return;
    int e = offs[node];
    const int end = offs[node + 1];
    unsigned sv = Gb[(size_t)node * 64 + lane];          // self-loop term
    float ax = bf16_lo(sv), ay = bf16_hi(sv);
    for (; e + 8 <= end; e += 8) {
        int j[8];
#pragma unroll
        for (int q = 0; q < 8; ++q) j[q] = csr[e + q];
        unsigned v[8];
#pragma unroll
        for (int q = 0; q < 8; ++q) v[q] = Gb[(size_t)j[q] * 64 + lane];
#pragma unroll
        for (int q = 0; q < 8; ++q) { ax += bf16_lo(v[q]); ay += bf16_hi(v[q]); }
    }
    for (; e + 4 <= end; e += 4) {
        int j0 = csr[e], j1 = csr[e + 1], j2 = csr[e + 2], j3 = csr[e + 3];
        unsigned v0 = Gb[(size_t)j0 * 64 + lane];
        unsigned v1 = Gb[(size_t)j1 * 64 + lane];
        unsigned v2 = Gb[(size_t)j2 * 64 + lane];
        unsigned v3 = Gb[(size_t)j3 * 64 + lane];
        ax += bf16_lo(v0) + bf16_lo(v1) + bf16_lo(v2) + bf16_lo(v3);
        ay += bf16_hi(v0) + bf16_hi(v1) + bf16_hi(v2) + bf16_hi(v3);
    }
    for (; e < end; ++e) {
        unsigned v = Gb[(size_t)csr[e] * 64 + lane];
        ax += bf16_lo(v); ay += bf16_hi(v);
    }
    float di = dinv[node];
    float2 o;
    o.x = fmaxf(ax * di + bias[lane * 2 + 0], 0.f);      // ReLU
    o.y = fmaxf(ay * di + bias[lane * 2 + 1], 0.f);
    *reinterpret_cast<float2*>(&out[(size_t)node * 128 + lane * 2]) = o;
}

// Layer-2 aggregate: 64 bf16 cols/row = 32 uints; two nodes per wave; 8-deep unroll.
__global__ __launch_bounds__(256) void agg2_kernel(const unsigned* __restrict__ Gb,
                                                   const int* __restrict__ offs,
                                                   const int* __restrict__ csr,
                                                   const float* __restrict__ dinv,
                                                   const float* __restrict__ bias,
                                                   float* __restrict__ out, int N) {
    int tid = blockIdx.x * blockDim.x + threadIdx.x;
    int node = (tid >> 6) * 2 + ((threadIdx.x >> 5) & 1);
    int c = threadIdx.x & 31;                            // uint column
    if (node >= N) return;
    int e = offs[node];
    const int end = offs[node + 1];
    unsigned sv = Gb[(size_t)node * 32 + c];
    float ax = bf16_lo(sv), ay = bf16_hi(sv);
    for (; e + 8 <= end; e += 8) {
        int j[8];
#pragma unroll
        for (int q = 0; q < 8; ++q) j[q] = csr[e + q];
        unsigned v[8];
#pragma unroll
        for (int q = 0; q < 8; ++q) v[q] = Gb[(size_t)j[q] * 32 + c];
#pragma unroll
        for (int q = 0; q < 8; ++q) { ax += bf16_lo(v[q]); ay += bf16_hi(v[q]); }
    }
    for (; e + 4 <= end; e += 4) {
        int j0 = csr[e], j1 = csr[e + 1], j2 = csr[e + 2], j3 = csr[e + 3];
        unsigned v0 = Gb[(size_t)j0 * 32 + c];
        unsigned v1 = Gb[(size_t)j1 * 32 + c];
        unsigned v2 = Gb[(size_t)j2 * 32 + c];
        unsigned v3 = Gb[(size_t)j3 * 32 + c];
        ax += bf16_lo(v0) + bf16_lo(v1) + bf16_lo(v2) + bf16_lo(v3);
        ay += bf16_hi(v0) + bf16_hi(v1) + bf16_hi(v2) + bf16_hi(v3);
    }
    for (; e < end; ++e) {
        unsigned v = Gb[(size_t)csr[e] * 32 + c];
        ax += bf16_lo(v); ay += bf16_hi(v);
    }
    float di = dinv[node];
    float2 o;
    o.x = ax * di + bias[c * 2 + 0];
    o.y = ay * di + bias[c * 2 + 1];
    *reinterpret_cast<float2*>(&out[(size_t)node * 64 + c * 2]) = o;
}

extern "C" void kernel_launch(void* const* d_in, const int* in_sizes, int n_in,
                              void* d_out, int out_size, void* d_ws, size_t ws_size,
                              hipStream_t stream) {
    const float* x  = (const float*)d_in[0];
    const int*   ei = (const int*)d_in[1];
    const float* W1 = (const float*)d_in[2];
    const float* b1 = (const float*)d_in[3];
    const float* W2 = (const float*)d_in[4];
    const float* b2 = (const float*)d_in[5];
    float* out = (float*)d_out;

    const int N = in_sizes[0] / 128;
    const int E = in_sizes[1] / 2;
    const int* src = ei;
    const int* dst = ei + E;
    const int nbkt = (N + 1023) >> 10;   // must be <= 256

    // Workspace layout
    unsigned* g1b = (unsigned*)d_ws;                 // N*64 uints (25.6MB) bf16 g1; reused as g2b
    float* a1 = (float*)(g1b + (size_t)N * 64);      // N*128 f32 (51.2MB)
    unsigned* g2b = g1b;                             // N*32 uints, aliases g1b
    int2* ebuf = (int2*)d_ws;                        // E*8B, aliases g1b (lifetime-disjoint)
    char* p = (char*)(a1 + (size_t)N * 128);
    int* cnt = (int*)p;    p += (((size_t)N * 4) + 15) & ~(size_t)15;
    float* dinv = (float*)p; p += (((size_t)N * 4) + 15) & ~(size_t)15;
    int* offs = (int*)p;   p += (((size_t)(N + 1) * 4) + 15) & ~(size_t)15;
    int* curs = (int*)p;   p += (((size_t)N * 4) + 15) & ~(size_t)15;
    int* csr = (int*)p;    p += (((size_t)E * 4) + 15) & ~(size_t)15;
    const int nscan = (N + 1023) / 1024;
    int* bsums = (int*)p;  p += (((size_t)nscan * 4) + 15) & ~(size_t)15;
    int* bcnt = (int*)p;   p += (((size_t)256 * 4) + 15) & ~(size_t)15;
    int* bcur = (int*)p;   p += (((size_t)256 * 4) + 15) & ~(size_t)15;
    if ((size_t)(p - (char*)d_ws) > ws_size || nbkt > 256 ||
        (size_t)E * 8 > (size_t)N * 64 * 4) return;  // fail loudly

    // --- graph preprocessing (once, shared by both layers) ---
    zero_i32<<<(N + 255) / 256, 256, 0, stream>>>(cnt, N);
    zero_i32<<<1, 256, 0, stream>>>(bcnt, 256);
    bucket_hist<<<1024, 256, 0, stream>>>(dst, bcnt, E, nbkt);
    bucket_scan<<<1, 256, 0, stream>>>(bcnt, bcur, nbkt);
    partition_kernel<<<(E + 4095) / 4096, 256, 0, stream>>>(src, dst, bcur, ebuf, E, nbkt);
    hist_bucketed<<<2048, 256, 0, stream>>>(ebuf, cnt, E);     // hot-window atomics
    dinv_kernel<<<(N + 255) / 256, 256, 0, stream>>>(cnt, dinv, N);
    scan_local<<<nscan, 256, 0, stream>>>(cnt, offs, bsums, N);
    scan_blocks<<<1, 1024, 0, stream>>>(bsums, nscan);
    scan_add<<<nscan, 256, 0, stream>>>(bsums, offs, curs, N, E);
    scatter_bucketed<<<2048, 256, 0, stream>>>(ebuf, curs, csr, E);

    // --- layer 1 ---
    gemm_scale<128><<<(N + 63) / 64, 256, 0, stream>>>(x, W1, dinv, g1b, N);
    agg1_kernel<<<(N + 3) / 4, 256, 0, stream>>>(g1b, offs, csr, dinv, b1, a1, N);

    // --- layer 2 ---
    gemm_scale<64><<<(N + 63) / 64, 256, 0, stream>>>(a1, W2, dinv, g2b, N);
    agg2_kernel<<<(N + 7) / 8, 256, 0, stream>>>(g2b, offs, csr, dinv, b2, out, N);
}

// Round 6
// 329.707 us; speedup vs baseline: 1.8768x; 1.1212x over previous
//
#include <hip/hip_runtime.h>
#include <hip/hip_bf16.h>

// ---------------------------------------------------------------------------
// 2-layer GCN. g[j] = dinv[j]*(X@W)[j] stored BF16; out[i] = dinv[i]*(g[i]+sum g[j]) + b
// CSR-by-destination built once, reused by both layers.
// R1: hierarchical scan (160us -> ~8us).
// R2: bucketed CSR scatter — kills 107MB write-thrash.
// R3: bf16 gather tables — halves edge-gather bytes.
// R5: bucketed degree hist; 8-deep gather unroll.
// R6: bf16 MFMA GEMMs (matrix pipe instead of f32 VALU); a1 stored bf16;
//     16-deep gather unroll ladder.
// ---------------------------------------------------------------------------

typedef short bf16x8 __attribute__((ext_vector_type(8)));
typedef float f32x4 __attribute__((ext_vector_type(4)));

__device__ __forceinline__ unsigned pack_bf16_2(float a, float b) {
    unsigned ua = __builtin_bit_cast(unsigned, a);
    unsigned ub = __builtin_bit_cast(unsigned, b);
    ua += 0x7FFFu + ((ua >> 16) & 1u);   // RNE to bf16
    ub += 0x7FFFu + ((ub >> 16) & 1u);
    return (ua >> 16) | (ub & 0xFFFF0000u);
}
__device__ __forceinline__ unsigned short bf16_1(float a) {
    unsigned ua = __builtin_bit_cast(unsigned, a);
    ua += 0x7FFFu + ((ua >> 16) & 1u);
    return (unsigned short)(ua >> 16);
}
__device__ __forceinline__ float bf16_lo(unsigned v) {
    return __builtin_bit_cast(float, v << 16);
}
__device__ __forceinline__ float bf16_hi(unsigned v) {
    return __builtin_bit_cast(float, v & 0xFFFF0000u);
}

__global__ void zero_i32(int* __restrict__ p, int n) {
    int i = blockIdx.x * blockDim.x + threadIdx.x;
    if (i < n) p[i] = 0;
}

__global__ void dinv_kernel(const int* __restrict__ cnt, float* __restrict__ dinv, int N) {
    int i = blockIdx.x * blockDim.x + threadIdx.x;
    if (i < N) dinv[i] = rsqrtf((float)(cnt[i] + 1));   // +1 = self-loop
}

// --- hierarchical scan over cnt -> offs (exclusive)
__global__ __launch_bounds__(256) void scan_local(const int* __restrict__ cnt,
                                                  int* __restrict__ offs,
                                                  int* __restrict__ bsums, int N) {
    __shared__ int tmp[256];
    const int tid = threadIdx.x;
    const int base = blockIdx.x * 1024 + tid * 4;
    int v[4];
#pragma unroll
    for (int i = 0; i < 4; ++i) v[i] = (base + i < N) ? cnt[base + i] : 0;
    const int tsum = v[0] + v[1] + v[2] + v[3];
    tmp[tid] = tsum;
    __syncthreads();
    int run = tsum;
    for (int off = 1; off < 256; off <<= 1) {
        int t = (tid >= off) ? tmp[tid - off] : 0;
        __syncthreads();
        run += t;
        tmp[tid] = run;
        __syncthreads();
    }
    int s = run - tsum;
#pragma unroll
    for (int i = 0; i < 4; ++i) {
        if (base + i < N) offs[base + i] = s;
        s += v[i];
    }
    if (tid == 255) bsums[blockIdx.x] = run;
}

__global__ __launch_bounds__(1024) void scan_blocks(int* __restrict__ bsums, int nb) {
    __shared__ int tmp[1024];
    const int tid = threadIdx.x;
    const int v = (tid < nb) ? bsums[tid] : 0;
    tmp[tid] = v;
    __syncthreads();
    int run = v;
    for (int off = 1; off < 1024; off <<= 1) {
        int t = (tid >= off) ? tmp[tid - off] : 0;
        __syncthreads();
        run += t;
        tmp[tid] = run;
        __syncthreads();
    }
    if (tid < nb) bsums[tid] = run - v;
}

__global__ __launch_bounds__(256) void scan_add(const int* __restrict__ bsums,
                                                int* __restrict__ offs,
                                                int* __restrict__ curs, int N, int E) {
    const int tid = threadIdx.x;
    const int base = blockIdx.x * 1024 + tid * 4;
    const int add = bsums[blockIdx.x];
#pragma unroll
    for (int i = 0; i < 4; ++i) {
        int idx = base + i;
        if (idx < N) {
            int o = offs[idx] + add;
            offs[idx] = o;
            curs[idx] = o;
        }
    }
    if (blockIdx.x == 0 && tid == 0) offs[N] = E;
}

// --- bucketed CSR scatter ---
__global__ void bucket_hist(const int* __restrict__ dst, int* __restrict__ bcnt, int E, int nb) {
    __shared__ int h[256];
    for (int t = threadIdx.x; t < nb; t += blockDim.x) h[t] = 0;
    __syncthreads();
    int stride = gridDim.x * blockDim.x;
    for (int e = blockIdx.x * blockDim.x + threadIdx.x; e < E; e += stride)
        atomicAdd(&h[dst[e] >> 10], 1);
    __syncthreads();
    for (int t = threadIdx.x; t < nb; t += blockDim.x)
        if (h[t]) atomicAdd(&bcnt[t], h[t]);
}

__global__ __launch_bounds__(256) void bucket_scan(const int* __restrict__ bcnt,
                                                   int* __restrict__ bcur, int nb) {
    __shared__ int tmp[256];
    const int tid = threadIdx.x;
    const int v = (tid < nb) ? bcnt[tid] : 0;
    tmp[tid] = v;
    __syncthreads();
    int run = v;
    for (int off = 1; off < 256; off <<= 1) {
        int t = (tid >= off) ? tmp[tid - off] : 0;
        __syncthreads();
        run += t;
        tmp[tid] = run;
        __syncthreads();
    }
    if (tid < nb) bcur[tid] = run - v;
}

__global__ __launch_bounds__(256) void partition_kernel(const int* __restrict__ src,
                                                        const int* __restrict__ dst,
                                                        int* __restrict__ bcur,
                                                        int2* __restrict__ ebuf,
                                                        int E, int nb) {
    __shared__ int hist[256];
    __shared__ int basel[256];
    const int tid = threadIdx.x;
    const int c0 = blockIdx.x * 4096;
    for (int t = tid; t < nb; t += 256) hist[t] = 0;
    __syncthreads();
    int s[16], d[16], r[16];
#pragma unroll
    for (int i = 0; i < 16; ++i) {
        int idx = c0 + i * 256 + tid;
        if (idx < E) {
            s[i] = src[idx];
            d[i] = dst[idx];
            r[i] = atomicAdd(&hist[d[i] >> 10], 1);
        } else {
            d[i] = -1;
        }
    }
    __syncthreads();
    for (int t = tid; t < nb; t += 256) basel[t] = hist[t] ? atomicAdd(&bcur[t], hist[t]) : 0;
    __syncthreads();
#pragma unroll
    for (int i = 0; i < 16; ++i) {
        if (d[i] >= 0) {
            int b = d[i] >> 10;
            ebuf[basel[b] + r[i]] = make_int2(s[i], d[i]);
        }
    }
}

// degree histogram over bucketed edges — atomics land in hot per-bucket windows.
__global__ void hist_bucketed(const int2* __restrict__ ebuf, int* __restrict__ cnt, int E) {
    int stride = gridDim.x * blockDim.x;
    for (int e = blockIdx.x * blockDim.x + threadIdx.x; e < E; e += stride)
        atomicAdd(&cnt[ebuf[e].y], 1);
}

__global__ void scatter_bucketed(const int2* __restrict__ ebuf, int* __restrict__ curs,
                                 int* __restrict__ csr, int E) {
    int stride = gridDim.x * blockDim.x;
    for (int e = blockIdx.x * blockDim.x + threadIdx.x; e < E; e += stride) {
        int2 p = ebuf[e];
        int pos = atomicAdd(&curs[p.y], 1);
        csr[pos] = p.x;
    }
}

// R6: MFMA GEMM. Gs[r*COUT+c] = bf16( dinv[r] * sum_k X[r,k]*W[k,c] ). K=128.
// Block: 256 thr = 4 waves, BR=64 rows (16/wave), full K staged.
// A frag: lane l holds A[row=l&15][k=(l>>4)*8+i]; B: col=l&15 same k pattern;
// D: col=l&15, row=(l>>4)*4+r (m89-verified mapping).
template <int COUT, bool INBF16>
__global__ __launch_bounds__(256) void gemm_mfma(const void* __restrict__ Xv,
                                                 const float* __restrict__ W,
                                                 const float* __restrict__ dinv,
                                                 unsigned short* __restrict__ Gs, int N) {
    constexpr int BR = 64;
    constexpr int CPT = COUT / 16;
    __shared__ unsigned short sx[BR][136];     // +8 bf16 pad: 272B row, 16B-aligned
    __shared__ unsigned short swT[COUT][136];  // W transposed [c][k]
    const int tid = threadIdx.x;
    const int r0 = blockIdx.x * BR;

    if constexpr (INBF16) {
        const unsigned* Xb = (const unsigned*)Xv;      // [N][64] packed bf16 pairs
#pragma unroll
        for (int q = 0; q < 4; ++q) {
            int off = q * 1024 + tid * 4;              // uint units in [64][64]
            int row = off >> 6;
            int ku = off & 63;
            size_t grow = (size_t)min(r0 + row, N - 1);
            uint4 v = *reinterpret_cast<const uint4*>(&Xb[grow * 64 + ku]);
            *reinterpret_cast<uint4*>(&sx[row][ku * 2]) = v;
        }
    } else {
        const float* Xf = (const float*)Xv;
#pragma unroll
        for (int q = 0; q < 8; ++q) {
            int off = q * 1024 + tid * 4;              // f32 units in [64][128]
            int row = off >> 7;
            int k = off & 127;
            size_t grow = (size_t)min(r0 + row, N - 1);
            float4 v = *reinterpret_cast<const float4*>(&Xf[grow * 128 + k]);
            uint2 pk;
            pk.x = pack_bf16_2(v.x, v.y);
            pk.y = pack_bf16_2(v.z, v.w);
            *reinterpret_cast<uint2*>(&sx[row][k]) = pk;
        }
    }
#pragma unroll
    for (int q = 0; q < COUT / 8; ++q) {
        int off = q * 1024 + tid * 4;                  // flat over [128][COUT]
        int k = off / COUT;
        int c = off % COUT;
        float4 v = *reinterpret_cast<const float4*>(&W[off]);
        swT[c + 0][k] = bf16_1(v.x);
        swT[c + 1][k] = bf16_1(v.y);
        swT[c + 2][k] = bf16_1(v.z);
        swT[c + 3][k] = bf16_1(v.w);
    }
    __syncthreads();

    const int w = tid >> 6;
    const int l = tid & 63;
    const int lr = l & 15;
    const int lkg = l >> 4;
    f32x4 acc[CPT];
#pragma unroll
    for (int c = 0; c < CPT; ++c) acc[c] = f32x4{0.f, 0.f, 0.f, 0.f};

#pragma unroll
    for (int ks = 0; ks < 4; ++ks) {
        const int k0 = ks * 32 + lkg * 8;
        bf16x8 a = *reinterpret_cast<const bf16x8*>(&sx[w * 16 + lr][k0]);
#pragma unroll
        for (int c = 0; c < CPT; ++c) {
            bf16x8 b = *reinterpret_cast<const bf16x8*>(&swT[c * 16 + lr][k0]);
            acc[c] = __builtin_amdgcn_mfma_f32_16x16x32_bf16(a, b, acc[c], 0, 0, 0);
        }
    }

#pragma unroll
    for (int r = 0; r < 4; ++r) {
        int gr = r0 + w * 16 + lkg * 4 + r;
        if (gr < N) {
            float di = dinv[gr];
#pragma unroll
            for (int c = 0; c < CPT; ++c)
                Gs[(size_t)gr * COUT + c * 16 + lr] = bf16_1(acc[c][r] * di);
        }
    }
}

// Layer-1 aggregate: 128 bf16 cols/row, one wave per node, 16-deep gather ladder.
// Writes a1 in packed bf16.
__global__ __launch_bounds__(256) void agg1_kernel(const unsigned* __restrict__ Gb,
                                                   const int* __restrict__ offs,
                                                   const int* __restrict__ csr,
                                                   const float* __restrict__ dinv,
                                                   const float* __restrict__ bias,
                                                   unsigned* __restrict__ outb, int N) {
    int node = (blockIdx.x * blockDim.x + threadIdx.x) >> 6;
    int lane = threadIdx.x & 63;
    if (node >= N) return;
    int e = offs[node];
    const int end = offs[node + 1];
    unsigned sv = Gb[(size_t)node * 64 + lane];          // self-loop term
    float ax = bf16_lo(sv), ay = bf16_hi(sv);
    for (; e + 16 <= end; e += 16) {
        int j[16];
#pragma unroll
        for (int q = 0; q < 16; ++q) j[q] = csr[e + q];
        unsigned v[16];
#pragma unroll
        for (int q = 0; q < 16; ++q) v[q] = Gb[(size_t)j[q] * 64 + lane];
#pragma unroll
        for (int q = 0; q < 16; ++q) { ax += bf16_lo(v[q]); ay += bf16_hi(v[q]); }
    }
    for (; e + 8 <= end; e += 8) {
        int j[8];
#pragma unroll
        for (int q = 0; q < 8; ++q) j[q] = csr[e + q];
        unsigned v[8];
#pragma unroll
        for (int q = 0; q < 8; ++q) v[q] = Gb[(size_t)j[q] * 64 + lane];
#pragma unroll
        for (int q = 0; q < 8; ++q) { ax += bf16_lo(v[q]); ay += bf16_hi(v[q]); }
    }
    for (; e + 4 <= end; e += 4) {
        int j0 = csr[e], j1 = csr[e + 1], j2 = csr[e + 2], j3 = csr[e + 3];
        unsigned v0 = Gb[(size_t)j0 * 64 + lane];
        unsigned v1 = Gb[(size_t)j1 * 64 + lane];
        unsigned v2 = Gb[(size_t)j2 * 64 + lane];
        unsigned v3 = Gb[(size_t)j3 * 64 + lane];
        ax += bf16_lo(v0) + bf16_lo(v1) + bf16_lo(v2) + bf16_lo(v3);
        ay += bf16_hi(v0) + bf16_hi(v1) + bf16_hi(v2) + bf16_hi(v3);
    }
    for (; e < end; ++e) {
        unsigned v = Gb[(size_t)csr[e] * 64 + lane];
        ax += bf16_lo(v); ay += bf16_hi(v);
    }
    float di = dinv[node];
    float ox = fmaxf(ax * di + bias[lane * 2 + 0], 0.f);     // ReLU
    float oy = fmaxf(ay * di + bias[lane * 2 + 1], 0.f);
    outb[(size_t)node * 64 + lane] = pack_bf16_2(ox, oy);
}

// Layer-2 aggregate: 64 bf16 cols/row = 32 uints; two nodes per wave; 16-deep ladder.
__global__ __launch_bounds__(256) void agg2_kernel(const unsigned* __restrict__ Gb,
                                                   const int* __restrict__ offs,
                                                   const int* __restrict__ csr,
                                                   const float* __restrict__ dinv,
                                                   const float* __restrict__ bias,
                                                   float* __restrict__ out, int N) {
    int tid = blockIdx.x * blockDim.x + threadIdx.x;
    int node = (tid >> 6) * 2 + ((threadIdx.x >> 5) & 1);
    int c = threadIdx.x & 31;                            // uint column
    if (node >= N) return;
    int e = offs[node];
    const int end = offs[node + 1];
    unsigned sv = Gb[(size_t)node * 32 + c];
    float ax = bf16_lo(sv), ay = bf16_hi(sv);
    for (; e + 16 <= end; e += 16) {
        int j[16];
#pragma unroll
        for (int q = 0; q < 16; ++q) j[q] = csr[e + q];
        unsigned v[16];
#pragma unroll
        for (int q = 0; q < 16; ++q) v[q] = Gb[(size_t)j[q] * 32 + c];
#pragma unroll
        for (int q = 0; q < 16; ++q) { ax += bf16_lo(v[q]); ay += bf16_hi(v[q]); }
    }
    for (; e + 8 <= end; e += 8) {
        int j[8];
#pragma unroll
        for (int q = 0; q < 8; ++q) j[q] = csr[e + q];
        unsigned v[8];
#pragma unroll
        for (int q = 0; q < 8; ++q) v[q] = Gb[(size_t)j[q] * 32 + c];
#pragma unroll
        for (int q = 0; q < 8; ++q) { ax += bf16_lo(v[q]); ay += bf16_hi(v[q]); }
    }
    for (; e + 4 <= end; e += 4) {
        int j0 = csr[e], j1 = csr[e + 1], j2 = csr[e + 2], j3 = csr[e + 3];
        unsigned v0 = Gb[(size_t)j0 * 32 + c];
        unsigned v1 = Gb[(size_t)j1 * 32 + c];
        unsigned v2 = Gb[(size_t)j2 * 32 + c];
        unsigned v3 = Gb[(size_t)j3 * 32 + c];
        ax += bf16_lo(v0) + bf16_lo(v1) + bf16_lo(v2) + bf16_lo(v3);
        ay += bf16_hi(v0) + bf16_hi(v1) + bf16_hi(v2) + bf16_hi(v3);
    }
    for (; e < end; ++e) {
        unsigned v = Gb[(size_t)csr[e] * 32 + c];
        ax += bf16_lo(v); ay += bf16_hi(v);
    }
    float di = dinv[node];
    float2 o;
    o.x = ax * di + bias[c * 2 + 0];
    o.y = ay * di + bias[c * 2 + 1];
    *reinterpret_cast<float2*>(&out[(size_t)node * 64 + c * 2]) = o;
}

extern "C" void kernel_launch(void* const* d_in, const int* in_sizes, int n_in,
                              void* d_out, int out_size, void* d_ws, size_t ws_size,
                              hipStream_t stream) {
    const float* x  = (const float*)d_in[0];
    const int*   ei = (const int*)d_in[1];
    const float* W1 = (const float*)d_in[2];
    const float* b1 = (const float*)d_in[3];
    const float* W2 = (const float*)d_in[4];
    const float* b2 = (const float*)d_in[5];
    float* out = (float*)d_out;

    const int N = in_sizes[0] / 128;
    const int E = in_sizes[1] / 2;
    const int* src = ei;
    const int* dst = ei + E;
    const int nbkt = (N + 1023) >> 10;   // must be <= 256

    // Workspace layout
    unsigned* g1b = (unsigned*)d_ws;                 // N*64 uints (25.6MB); reused as g2b
    unsigned* a1b = g1b + (size_t)N * 64;            // N*64 uints (25.6MB) bf16 a1
    unsigned* g2b = g1b;                             // N*32 uints, aliases g1b
    int2* ebuf = (int2*)d_ws;                        // E*8B, aliases g1b (lifetime-disjoint)
    char* p = (char*)(a1b + (size_t)N * 64);
    int* cnt = (int*)p;    p += (((size_t)N * 4) + 15) & ~(size_t)15;
    float* dinv = (float*)p; p += (((size_t)N * 4) + 15) & ~(size_t)15;
    int* offs = (int*)p;   p += (((size_t)(N + 1) * 4) + 15) & ~(size_t)15;
    int* curs = (int*)p;   p += (((size_t)N * 4) + 15) & ~(size_t)15;
    int* csr = (int*)p;    p += (((size_t)E * 4) + 15) & ~(size_t)15;
    const int nscan = (N + 1023) / 1024;
    int* bsums = (int*)p;  p += (((size_t)nscan * 4) + 15) & ~(size_t)15;
    int* bcnt = (int*)p;   p += (((size_t)256 * 4) + 15) & ~(size_t)15;
    int* bcur = (int*)p;   p += (((size_t)256 * 4) + 15) & ~(size_t)15;
    if ((size_t)(p - (char*)d_ws) > ws_size || nbkt > 256 ||
        (size_t)E * 8 > (size_t)N * 64 * 4) return;  // fail loudly

    // --- graph preprocessing (once, shared by both layers) ---
    zero_i32<<<(N + 255) / 256, 256, 0, stream>>>(cnt, N);
    zero_i32<<<1, 256, 0, stream>>>(bcnt, 256);
    bucket_hist<<<1024, 256, 0, stream>>>(dst, bcnt, E, nbkt);
    bucket_scan<<<1, 256, 0, stream>>>(bcnt, bcur, nbkt);
    partition_kernel<<<(E + 4095) / 4096, 256, 0, stream>>>(src, dst, bcur, ebuf, E, nbkt);
    hist_bucketed<<<2048, 256, 0, stream>>>(ebuf, cnt, E);
    dinv_kernel<<<(N + 255) / 256, 256, 0, stream>>>(cnt, dinv, N);
    scan_local<<<nscan, 256, 0, stream>>>(cnt, offs, bsums, N);
    scan_blocks<<<1, 1024, 0, stream>>>(bsums, nscan);
    scan_add<<<nscan, 256, 0, stream>>>(bsums, offs, curs, N, E);
    scatter_bucketed<<<2048, 256, 0, stream>>>(ebuf, curs, csr, E);

    // --- layer 1 ---
    gemm_mfma<128, false><<<(N + 63) / 64, 256, 0, stream>>>(
        x, W1, dinv, (unsigned short*)g1b, N);
    agg1_kernel<<<(N + 3) / 4, 256, 0, stream>>>(g1b, offs, csr, dinv, b1, a1b, N);

    // --- layer 2 ---
    gemm_mfma<64, true><<<(N + 63) / 64, 256, 0, stream>>>(
        a1b, W2, dinv, (unsigned short*)g2b, N);
    agg2_kernel<<<(N + 7) / 8, 256, 0, stream>>>(g2b, offs, csr, dinv, b2, out, N);
}

// Round 7
// 257.909 us; speedup vs baseline: 2.3992x; 1.2784x over previous
//
#include <hip/hip_runtime.h>
#include <hip/hip_bf16.h>

// ---------------------------------------------------------------------------
// 2-layer GCN. g[j] = dinv[j]*(X@W)[j] stored BF16; out[i] = dinv[i]*(g[i]+sum g[j]) + b
// CSR-by-destination built once, reused by both layers.
// R1: hierarchical scan. R2: bucketed CSR scatter. R3: bf16 gather tables.
// R5: bucketed degree hist; deep gather unroll. R6: bf16 MFMA GEMMs; bf16 a1.
// R7: single-kernel per-bucket CSR build (replaces 5 preprocessing dispatches:
//     hist_bucketed + 3-phase scan + scatter_bucketed + dinv, all via LDS).
// ---------------------------------------------------------------------------

typedef short bf16x8 __attribute__((ext_vector_type(8)));
typedef float f32x4 __attribute__((ext_vector_type(4)));

__device__ __forceinline__ unsigned pack_bf16_2(float a, float b) {
    unsigned ua = __builtin_bit_cast(unsigned, a);
    unsigned ub = __builtin_bit_cast(unsigned, b);
    ua += 0x7FFFu + ((ua >> 16) & 1u);   // RNE to bf16
    ub += 0x7FFFu + ((ub >> 16) & 1u);
    return (ua >> 16) | (ub & 0xFFFF0000u);
}
__device__ __forceinline__ unsigned short bf16_1(float a) {
    unsigned ua = __builtin_bit_cast(unsigned, a);
    ua += 0x7FFFu + ((ua >> 16) & 1u);
    return (unsigned short)(ua >> 16);
}
__device__ __forceinline__ float bf16_lo(unsigned v) {
    return __builtin_bit_cast(float, v << 16);
}
__device__ __forceinline__ float bf16_hi(unsigned v) {
    return __builtin_bit_cast(float, v & 0xFFFF0000u);
}

__global__ void zero_i32(int* __restrict__ p, int n) {
    int i = blockIdx.x * blockDim.x + threadIdx.x;
    if (i < n) p[i] = 0;
}

// --- bucket edges by dst>>10 ---
__global__ void bucket_hist(const int* __restrict__ dst, int* __restrict__ bcnt, int E, int nb) {
    __shared__ int h[256];
    for (int t = threadIdx.x; t < nb; t += blockDim.x) h[t] = 0;
    __syncthreads();
    int stride = gridDim.x * blockDim.x;
    for (int e = blockIdx.x * blockDim.x + threadIdx.x; e < E; e += stride)
        atomicAdd(&h[dst[e] >> 10], 1);
    __syncthreads();
    for (int t = threadIdx.x; t < nb; t += blockDim.x)
        if (h[t]) atomicAdd(&bcnt[t], h[t]);
}

__global__ __launch_bounds__(256) void bucket_scan(const int* __restrict__ bcnt,
                                                   int* __restrict__ bbase,
                                                   int* __restrict__ bcur, int nb, int E) {
    __shared__ int tmp[256];
    const int tid = threadIdx.x;
    const int v = (tid < nb) ? bcnt[tid] : 0;
    tmp[tid] = v;
    __syncthreads();
    int run = v;
    for (int off = 1; off < 256; off <<= 1) {
        int t = (tid >= off) ? tmp[tid - off] : 0;
        __syncthreads();
        run += t;
        tmp[tid] = run;
        __syncthreads();
    }
    if (tid < nb) {
        int ex = run - v;
        bbase[tid] = ex;
        bcur[tid] = ex;
    }
    if (tid == 0) bbase[nb] = E;
}

__global__ __launch_bounds__(256) void partition_kernel(const int* __restrict__ src,
                                                        const int* __restrict__ dst,
                                                        int* __restrict__ bcur,
                                                        int2* __restrict__ ebuf,
                                                        int E, int nb) {
    __shared__ int hist[256];
    __shared__ int basel[256];
    const int tid = threadIdx.x;
    const int c0 = blockIdx.x * 4096;
    for (int t = tid; t < nb; t += 256) hist[t] = 0;
    __syncthreads();
    int s[16], d[16], r[16];
#pragma unroll
    for (int i = 0; i < 16; ++i) {
        int idx = c0 + i * 256 + tid;
        if (idx < E) {
            s[i] = src[idx];
            d[i] = dst[idx];
            r[i] = atomicAdd(&hist[d[i] >> 10], 1);
        } else {
            d[i] = -1;
        }
    }
    __syncthreads();
    for (int t = tid; t < nb; t += 256) basel[t] = hist[t] ? atomicAdd(&bcur[t], hist[t]) : 0;
    __syncthreads();
#pragma unroll
    for (int i = 0; i < 16; ++i) {
        if (d[i] >= 0) {
            int b = d[i] >> 10;
            ebuf[basel[b] + r[i]] = make_int2(s[i], d[i]);
        }
    }
}

// R7: one block per dst-bucket. Streams the bucket's edge range twice:
// pass A: LDS degree histogram -> block scan -> offs, dinv;
// pass B: LDS cursors -> csr placement. All atomics in LDS.
__global__ __launch_bounds__(256) void csr_build(const int2* __restrict__ ebuf,
                                                 const int* __restrict__ bbase,
                                                 int* __restrict__ offs,
                                                 float* __restrict__ dinv,
                                                 int* __restrict__ csr,
                                                 int N, int E) {
    __shared__ int hist[1024];
    __shared__ int lofs[1024];
    __shared__ int stmp[256];
    const int b = blockIdx.x;
    const int tid = threadIdx.x;
    const int n0 = b << 10;
    const int e0 = bbase[b], e1 = bbase[b + 1];
#pragma unroll
    for (int q = 0; q < 4; ++q) hist[tid + q * 256] = 0;
    __syncthreads();
    for (int e = e0 + tid; e < e1; e += 256)
        atomicAdd(&hist[ebuf[e].y & 1023], 1);
    __syncthreads();
    // block-local exclusive scan of 1024 degrees (4/thread)
    const int base4 = tid * 4;
    int v[4];
#pragma unroll
    for (int q = 0; q < 4; ++q) v[q] = hist[base4 + q];
    const int tsum = v[0] + v[1] + v[2] + v[3];
    stmp[tid] = tsum;
    __syncthreads();
    int run = tsum;
    for (int off = 1; off < 256; off <<= 1) {
        int t = (tid >= off) ? stmp[tid - off] : 0;
        __syncthreads();
        run += t;
        stmp[tid] = run;
        __syncthreads();
    }
    int s = run - tsum;
#pragma unroll
    for (int q = 0; q < 4; ++q) { lofs[base4 + q] = s; s += v[q]; }
    __syncthreads();
#pragma unroll
    for (int q = 0; q < 4; ++q) {
        int il = tid + q * 256;
        int node = n0 + il;
        if (node < N) {
            offs[node] = e0 + lofs[il];
            dinv[node] = rsqrtf((float)(hist[il] + 1));   // +1 self-loop
        }
    }
    __syncthreads();
    // pass B: place edges via LDS cursors (lofs reused in place)
    for (int e = e0 + tid; e < e1; e += 256) {
        int2 p = ebuf[e];
        int pos = atomicAdd(&lofs[p.y & 1023], 1);
        csr[e0 + pos] = p.x;
    }
    if (b == 0 && tid == 0) offs[N] = E;
}

// MFMA GEMM. Gs[r*COUT+c] = bf16( dinv[r] * sum_k X[r,k]*W[k,c] ). K=128.
template <int COUT, bool INBF16>
__global__ __launch_bounds__(256) void gemm_mfma(const void* __restrict__ Xv,
                                                 const float* __restrict__ W,
                                                 const float* __restrict__ dinv,
                                                 unsigned short* __restrict__ Gs, int N) {
    constexpr int BR = 64;
    constexpr int CPT = COUT / 16;
    __shared__ unsigned short sx[BR][136];
    __shared__ unsigned short swT[COUT][136];
    const int tid = threadIdx.x;
    const int r0 = blockIdx.x * BR;

    if constexpr (INBF16) {
        const unsigned* Xb = (const unsigned*)Xv;
#pragma unroll
        for (int q = 0; q < 4; ++q) {
            int off = q * 1024 + tid * 4;
            int row = off >> 6;
            int ku = off & 63;
            size_t grow = (size_t)min(r0 + row, N - 1);
            uint4 v = *reinterpret_cast<const uint4*>(&Xb[grow * 64 + ku]);
            *reinterpret_cast<uint4*>(&sx[row][ku * 2]) = v;
        }
    } else {
        const float* Xf = (const float*)Xv;
#pragma unroll
        for (int q = 0; q < 8; ++q) {
            int off = q * 1024 + tid * 4;
            int row = off >> 7;
            int k = off & 127;
            size_t grow = (size_t)min(r0 + row, N - 1);
            float4 v = *reinterpret_cast<const float4*>(&Xf[grow * 128 + k]);
            uint2 pk;
            pk.x = pack_bf16_2(v.x, v.y);
            pk.y = pack_bf16_2(v.z, v.w);
            *reinterpret_cast<uint2*>(&sx[row][k]) = pk;
        }
    }
#pragma unroll
    for (int q = 0; q < COUT / 8; ++q) {
        int off = q * 1024 + tid * 4;
        int k = off / COUT;
        int c = off % COUT;
        float4 v = *reinterpret_cast<const float4*>(&W[off]);
        swT[c + 0][k] = bf16_1(v.x);
        swT[c + 1][k] = bf16_1(v.y);
        swT[c + 2][k] = bf16_1(v.z);
        swT[c + 3][k] = bf16_1(v.w);
    }
    __syncthreads();

    const int w = tid >> 6;
    const int l = tid & 63;
    const int lr = l & 15;
    const int lkg = l >> 4;
    f32x4 acc[CPT];
#pragma unroll
    for (int c = 0; c < CPT; ++c) acc[c] = f32x4{0.f, 0.f, 0.f, 0.f};

#pragma unroll
    for (int ks = 0; ks < 4; ++ks) {
        const int k0 = ks * 32 + lkg * 8;
        bf16x8 a = *reinterpret_cast<const bf16x8*>(&sx[w * 16 + lr][k0]);
#pragma unroll
        for (int c = 0; c < CPT; ++c) {
            bf16x8 b = *reinterpret_cast<const bf16x8*>(&swT[c * 16 + lr][k0]);
            acc[c] = __builtin_amdgcn_mfma_f32_16x16x32_bf16(a, b, acc[c], 0, 0, 0);
        }
    }

#pragma unroll
    for (int r = 0; r < 4; ++r) {
        int gr = r0 + w * 16 + lkg * 4 + r;
        if (gr < N) {
            float di = dinv[gr];
#pragma unroll
            for (int c = 0; c < CPT; ++c)
                Gs[(size_t)gr * COUT + c * 16 + lr] = bf16_1(acc[c][r] * di);
        }
    }
}

// Layer-1 aggregate: 128 bf16 cols/row, one wave per node, 16-deep gather ladder.
__global__ __launch_bounds__(256) void agg1_kernel(const unsigned* __restrict__ Gb,
                                                   const int* __restrict__ offs,
                                                   const int* __restrict__ csr,
                                                   const float* __restrict__ dinv,
                                                   const float* __restrict__ bias,
                                                   unsigned* __restrict__ outb, int N) {
    int node = (blockIdx.x * blockDim.x + threadIdx.x) >> 6;
    int lane = threadIdx.x & 63;
    if (node >= N) return;
    int e = offs[node];
    const int end = offs[node + 1];
    unsigned sv = Gb[(size_t)node * 64 + lane];
    float ax = bf16_lo(sv), ay = bf16_hi(sv);
    for (; e + 16 <= end; e += 16) {
        int j[16];
#pragma unroll
        for (int q = 0; q < 16; ++q) j[q] = csr[e + q];
        unsigned v[16];
#pragma unroll
        for (int q = 0; q < 16; ++q) v[q] = Gb[(size_t)j[q] * 64 + lane];
#pragma unroll
        for (int q = 0; q < 16; ++q) { ax += bf16_lo(v[q]); ay += bf16_hi(v[q]); }
    }
    for (; e + 8 <= end; e += 8) {
        int j[8];
#pragma unroll
        for (int q = 0; q < 8; ++q) j[q] = csr[e + q];
        unsigned v[8];
#pragma unroll
        for (int q = 0; q < 8; ++q) v[q] = Gb[(size_t)j[q] * 64 + lane];
#pragma unroll
        for (int q = 0; q < 8; ++q) { ax += bf16_lo(v[q]); ay += bf16_hi(v[q]); }
    }
    for (; e + 4 <= end; e += 4) {
        int j0 = csr[e], j1 = csr[e + 1], j2 = csr[e + 2], j3 = csr[e + 3];
        unsigned v0 = Gb[(size_t)j0 * 64 + lane];
        unsigned v1 = Gb[(size_t)j1 * 64 + lane];
        unsigned v2 = Gb[(size_t)j2 * 64 + lane];
        unsigned v3 = Gb[(size_t)j3 * 64 + lane];
        ax += bf16_lo(v0) + bf16_lo(v1) + bf16_lo(v2) + bf16_lo(v3);
        ay += bf16_hi(v0) + bf16_hi(v1) + bf16_hi(v2) + bf16_hi(v3);
    }
    for (; e < end; ++e) {
        unsigned v = Gb[(size_t)csr[e] * 64 + lane];
        ax += bf16_lo(v); ay += bf16_hi(v);
    }
    float di = dinv[node];
    float ox = fmaxf(ax * di + bias[lane * 2 + 0], 0.f);
    float oy = fmaxf(ay * di + bias[lane * 2 + 1], 0.f);
    outb[(size_t)node * 64 + lane] = pack_bf16_2(ox, oy);
}

// Layer-2 aggregate: 64 bf16 cols/row = 32 uints; two nodes per wave; 16-deep ladder.
__global__ __launch_bounds__(256) void agg2_kernel(const unsigned* __restrict__ Gb,
                                                   const int* __restrict__ offs,
                                                   const int* __restrict__ csr,
                                                   const float* __restrict__ dinv,
                                                   const float* __restrict__ bias,
                                                   float* __restrict__ out, int N) {
    int tid = blockIdx.x * blockDim.x + threadIdx.x;
    int node = (tid >> 6) * 2 + ((threadIdx.x >> 5) & 1);
    int c = threadIdx.x & 31;
    if (node >= N) return;
    int e = offs[node];
    const int end = offs[node + 1];
    unsigned sv = Gb[(size_t)node * 32 + c];
    float ax = bf16_lo(sv), ay = bf16_hi(sv);
    for (; e + 16 <= end; e += 16) {
        int j[16];
#pragma unroll
        for (int q = 0; q < 16; ++q) j[q] = csr[e + q];
        unsigned v[16];
#pragma unroll
        for (int q = 0; q < 16; ++q) v[q] = Gb[(size_t)j[q] * 32 + c];
#pragma unroll
        for (int q = 0; q < 16; ++q) { ax += bf16_lo(v[q]); ay += bf16_hi(v[q]); }
    }
    for (; e + 8 <= end; e += 8) {
        int j[8];
#pragma unroll
        for (int q = 0; q < 8; ++q) j[q] = csr[e + q];
        unsigned v[8];
#pragma unroll
        for (int q = 0; q < 8; ++q) v[q] = Gb[(size_t)j[q] * 32 + c];
#pragma unroll
        for (int q = 0; q < 8; ++q) { ax += bf16_lo(v[q]); ay += bf16_hi(v[q]); }
    }
    for (; e + 4 <= end; e += 4) {
        int j0 = csr[e], j1 = csr[e + 1], j2 = csr[e + 2], j3 = csr[e + 3];
        unsigned v0 = Gb[(size_t)j0 * 32 + c];
        unsigned v1 = Gb[(size_t)j1 * 32 + c];
        unsigned v2 = Gb[(size_t)j2 * 32 + c];
        unsigned v3 = Gb[(size_t)j3 * 32 + c];
        ax += bf16_lo(v0) + bf16_lo(v1) + bf16_lo(v2) + bf16_lo(v3);
        ay += bf16_hi(v0) + bf16_hi(v1) + bf16_hi(v2) + bf16_hi(v3);
    }
    for (; e < end; ++e) {
        unsigned v = Gb[(size_t)csr[e] * 32 + c];
        ax += bf16_lo(v); ay += bf16_hi(v);
    }
    float di = dinv[node];
    float2 o;
    o.x = ax * di + bias[c * 2 + 0];
    o.y = ay * di + bias[c * 2 + 1];
    *reinterpret_cast<float2*>(&out[(size_t)node * 64 + c * 2]) = o;
}

extern "C" void kernel_launch(void* const* d_in, const int* in_sizes, int n_in,
                              void* d_out, int out_size, void* d_ws, size_t ws_size,
                              hipStream_t stream) {
    const float* x  = (const float*)d_in[0];
    const int*   ei = (const int*)d_in[1];
    const float* W1 = (const float*)d_in[2];
    const float* b1 = (const float*)d_in[3];
    const float* W2 = (const float*)d_in[4];
    const float* b2 = (const float*)d_in[5];
    float* out = (float*)d_out;

    const int N = in_sizes[0] / 128;
    const int E = in_sizes[1] / 2;
    const int* src = ei;
    const int* dst = ei + E;
    const int nbkt = (N + 1023) >> 10;   // must be <= 256

    // Workspace layout
    unsigned* g1b = (unsigned*)d_ws;                 // N*64 uints (25.6MB); reused as g2b
    unsigned* a1b = g1b + (size_t)N * 64;            // N*64 uints bf16 a1
    unsigned* g2b = g1b;
    int2* ebuf = (int2*)d_ws;                        // E*8B, aliases g1b (lifetime-disjoint)
    char* p = (char*)(a1b + (size_t)N * 64);
    float* dinv = (float*)p; p += (((size_t)N * 4) + 15) & ~(size_t)15;
    int* offs = (int*)p;   p += (((size_t)(N + 1) * 4) + 15) & ~(size_t)15;
    int* csr = (int*)p;    p += (((size_t)E * 4) + 15) & ~(size_t)15;
    int* bcnt = (int*)p;   p += (((size_t)256 * 4) + 15) & ~(size_t)15;
    int* bcur = (int*)p;   p += (((size_t)256 * 4) + 15) & ~(size_t)15;
    int* bbase = (int*)p;  p += (((size_t)257 * 4) + 15) & ~(size_t)15;
    if ((size_t)(p - (char*)d_ws) > ws_size || nbkt > 256 ||
        (size_t)E * 8 > (size_t)N * 64 * 4) return;  // fail loudly

    // --- graph preprocessing (5 dispatches) ---
    zero_i32<<<1, 256, 0, stream>>>(bcnt, 256);
    bucket_hist<<<1024, 256, 0, stream>>>(dst, bcnt, E, nbkt);
    bucket_scan<<<1, 256, 0, stream>>>(bcnt, bbase, bcur, nbkt, E);
    partition_kernel<<<(E + 4095) / 4096, 256, 0, stream>>>(src, dst, bcur, ebuf, E, nbkt);
    csr_build<<<nbkt, 256, 0, stream>>>(ebuf, bbase, offs, dinv, csr, N, E);

    // --- layer 1 ---
    gemm_mfma<128, false><<<(N + 63) / 64, 256, 0, stream>>>(
        x, W1, dinv, (unsigned short*)g1b, N);
    agg1_kernel<<<(N + 3) / 4, 256, 0, stream>>>(g1b, offs, csr, dinv, b1, a1b, N);

    // --- layer 2 ---
    gemm_mfma<64, true><<<(N + 63) / 64, 256, 0, stream>>>(
        a1b, W2, dinv, (unsigned short*)g2b, N);
    agg2_kernel<<<(N + 7) / 8, 256, 0, stream>>>(g2b, offs, csr, dinv, b2, out, N);
}

// Round 8
// 220.421 us; speedup vs baseline: 2.8073x; 1.1701x over previous
//
#include <hip/hip_runtime.h>
#include <hip/hip_bf16.h>

// ---------------------------------------------------------------------------
// 2-layer GCN. g[j] = dinv[j]*(X@W)[j] stored BF16; out[i] = dinv[i]*(g[i]+sum g[j]) + b
// CSR-by-destination built once, reused by both layers.
// R1: hierarchical scan. R2: bucketed CSR scatter. R3: bf16 gather tables.
// R5: bucketed degree hist; deep gather unroll. R6: bf16 MFMA GEMMs; bf16 a1.
// R7: single-kernel per-bucket CSR build.
// R8: fixed-capacity buckets — drops the bucket-count prepass (9 -> 7 dispatches);
//     csr_build derives bucket bases from an in-kernel 98-elem scan.
// ---------------------------------------------------------------------------

typedef short bf16x8 __attribute__((ext_vector_type(8)));
typedef float f32x4 __attribute__((ext_vector_type(4)));

__device__ __forceinline__ unsigned pack_bf16_2(float a, float b) {
    unsigned ua = __builtin_bit_cast(unsigned, a);
    unsigned ub = __builtin_bit_cast(unsigned, b);
    ua += 0x7FFFu + ((ua >> 16) & 1u);   // RNE to bf16
    ub += 0x7FFFu + ((ub >> 16) & 1u);
    return (ua >> 16) | (ub & 0xFFFF0000u);
}
__device__ __forceinline__ unsigned short bf16_1(float a) {
    unsigned ua = __builtin_bit_cast(unsigned, a);
    ua += 0x7FFFu + ((ua >> 16) & 1u);
    return (unsigned short)(ua >> 16);
}
__device__ __forceinline__ float bf16_lo(unsigned v) {
    return __builtin_bit_cast(float, v << 16);
}
__device__ __forceinline__ float bf16_hi(unsigned v) {
    return __builtin_bit_cast(float, v & 0xFFFF0000u);
}

// R8: partition edges into fixed-capacity dst-buckets (bucket b = dst>>10 at
// ebuf[b*cap ...]). bcur[b] is a global running count (L2-hot, 98 ints).
__global__ __launch_bounds__(256) void partition_fixed(const int* __restrict__ src,
                                                       const int* __restrict__ dst,
                                                       int* __restrict__ bcur,
                                                       int2* __restrict__ ebuf,
                                                       int E, int nb, int cap) {
    __shared__ int hist[256];
    __shared__ int basel[256];
    const int tid = threadIdx.x;
    const int c0 = blockIdx.x * 4096;
    for (int t = tid; t < nb; t += 256) hist[t] = 0;
    __syncthreads();
    int s[16], d[16], r[16];
#pragma unroll
    for (int i = 0; i < 16; ++i) {
        int idx = c0 + i * 256 + tid;
        if (idx < E) {
            s[i] = src[idx];
            d[i] = dst[idx];
            r[i] = atomicAdd(&hist[d[i] >> 10], 1);
        } else {
            d[i] = -1;
        }
    }
    __syncthreads();
    for (int t = tid; t < nb; t += 256) basel[t] = hist[t] ? atomicAdd(&bcur[t], hist[t]) : 0;
    __syncthreads();
#pragma unroll
    for (int i = 0; i < 16; ++i) {
        if (d[i] >= 0) {
            int b = d[i] >> 10;
            int pos = basel[b] + r[i];
            if (pos < cap)   // overflow guard (loud failure: dropped edge -> absmax blows)
                ebuf[(size_t)b * cap + pos] = make_int2(s[i], d[i]);
        }
    }
}

// One block per dst-bucket. Derives bucket bases from a 98-elem scan of bcur,
// then: pass A: LDS degree hist -> block scan -> offs, dinv;
//       pass B: LDS cursors -> compact csr placement. All heavy atomics in LDS.
__global__ __launch_bounds__(256) void csr_build(const int2* __restrict__ ebuf,
                                                 const int* __restrict__ bcur,
                                                 int* __restrict__ offs,
                                                 float* __restrict__ dinv,
                                                 int* __restrict__ csr,
                                                 int N, int E, int nb, int cap) {
    __shared__ int hist[1024];
    __shared__ int lofs[1024];
    __shared__ int stmp[256];
    __shared__ int s_e0, s_cnt;
    const int b = blockIdx.x;
    const int tid = threadIdx.x;
    const int n0 = b << 10;

    // exclusive base of this bucket in the compact csr = scan of bcur counts
    {
        int bc = (tid < nb) ? bcur[tid] : 0;
        stmp[tid] = bc;
        __syncthreads();
        int run = bc;
        for (int off = 1; off < 256; off <<= 1) {
            int t = (tid >= off) ? stmp[tid - off] : 0;
            __syncthreads();
            run += t;
            stmp[tid] = run;
            __syncthreads();
        }
        if (tid == b) { s_cnt = bc; s_e0 = run - bc; }
        __syncthreads();
    }
    const int e0 = s_e0;
    const int cnt = s_cnt;
    const int2* eb = ebuf + (size_t)b * cap;

#pragma unroll
    for (int q = 0; q < 4; ++q) hist[tid + q * 256] = 0;
    __syncthreads();
    for (int e = tid; e < cnt; e += 256)
        atomicAdd(&hist[eb[e].y & 1023], 1);
    __syncthreads();
    // block-local exclusive scan of 1024 degrees (4/thread)
    const int base4 = tid * 4;
    int v[4];
#pragma unroll
    for (int q = 0; q < 4; ++q) v[q] = hist[base4 + q];
    const int tsum = v[0] + v[1] + v[2] + v[3];
    stmp[tid] = tsum;
    __syncthreads();
    int run = tsum;
    for (int off = 1; off < 256; off <<= 1) {
        int t = (tid >= off) ? stmp[tid - off] : 0;
        __syncthreads();
        run += t;
        stmp[tid] = run;
        __syncthreads();
    }
    int s = run - tsum;
#pragma unroll
    for (int q = 0; q < 4; ++q) { lofs[base4 + q] = s; s += v[q]; }
    __syncthreads();
#pragma unroll
    for (int q = 0; q < 4; ++q) {
        int il = tid + q * 256;
        int node = n0 + il;
        if (node < N) {
            offs[node] = e0 + lofs[il];
            dinv[node] = rsqrtf((float)(hist[il] + 1));   // +1 self-loop
        }
    }
    __syncthreads();
    // pass B: place edges via LDS cursors (lofs reused in place)
    for (int e = tid; e < cnt; e += 256) {
        int2 p = eb[e];
        int pos = atomicAdd(&lofs[p.y & 1023], 1);
        csr[e0 + pos] = p.x;
    }
    if (b == 0 && tid == 0) offs[N] = E;
}

// MFMA GEMM. Gs[r*COUT+c] = bf16( dinv[r] * sum_k X[r,k]*W[k,c] ). K=128.
template <int COUT, bool INBF16>
__global__ __launch_bounds__(256) void gemm_mfma(const void* __restrict__ Xv,
                                                 const float* __restrict__ W,
                                                 const float* __restrict__ dinv,
                                                 unsigned short* __restrict__ Gs, int N) {
    constexpr int BR = 64;
    constexpr int CPT = COUT / 16;
    __shared__ unsigned short sx[BR][136];
    __shared__ unsigned short swT[COUT][136];
    const int tid = threadIdx.x;
    const int r0 = blockIdx.x * BR;

    if constexpr (INBF16) {
        const unsigned* Xb = (const unsigned*)Xv;
#pragma unroll
        for (int q = 0; q < 4; ++q) {
            int off = q * 1024 + tid * 4;
            int row = off >> 6;
            int ku = off & 63;
            size_t grow = (size_t)min(r0 + row, N - 1);
            uint4 v = *reinterpret_cast<const uint4*>(&Xb[grow * 64 + ku]);
            *reinterpret_cast<uint4*>(&sx[row][ku * 2]) = v;
        }
    } else {
        const float* Xf = (const float*)Xv;
#pragma unroll
        for (int q = 0; q < 8; ++q) {
            int off = q * 1024 + tid * 4;
            int row = off >> 7;
            int k = off & 127;
            size_t grow = (size_t)min(r0 + row, N - 1);
            float4 v = *reinterpret_cast<const float4*>(&Xf[grow * 128 + k]);
            uint2 pk;
            pk.x = pack_bf16_2(v.x, v.y);
            pk.y = pack_bf16_2(v.z, v.w);
            *reinterpret_cast<uint2*>(&sx[row][k]) = pk;
        }
    }
#pragma unroll
    for (int q = 0; q < COUT / 8; ++q) {
        int off = q * 1024 + tid * 4;
        int k = off / COUT;
        int c = off % COUT;
        float4 v = *reinterpret_cast<const float4*>(&W[off]);
        swT[c + 0][k] = bf16_1(v.x);
        swT[c + 1][k] = bf16_1(v.y);
        swT[c + 2][k] = bf16_1(v.z);
        swT[c + 3][k] = bf16_1(v.w);
    }
    __syncthreads();

    const int w = tid >> 6;
    const int l = tid & 63;
    const int lr = l & 15;
    const int lkg = l >> 4;
    f32x4 acc[CPT];
#pragma unroll
    for (int c = 0; c < CPT; ++c) acc[c] = f32x4{0.f, 0.f, 0.f, 0.f};

#pragma unroll
    for (int ks = 0; ks < 4; ++ks) {
        const int k0 = ks * 32 + lkg * 8;
        bf16x8 a = *reinterpret_cast<const bf16x8*>(&sx[w * 16 + lr][k0]);
#pragma unroll
        for (int c = 0; c < CPT; ++c) {
            bf16x8 b = *reinterpret_cast<const bf16x8*>(&swT[c * 16 + lr][k0]);
            acc[c] = __builtin_amdgcn_mfma_f32_16x16x32_bf16(a, b, acc[c], 0, 0, 0);
        }
    }

#pragma unroll
    for (int r = 0; r < 4; ++r) {
        int gr = r0 + w * 16 + lkg * 4 + r;
        if (gr < N) {
            float di = dinv[gr];
#pragma unroll
            for (int c = 0; c < CPT; ++c)
                Gs[(size_t)gr * COUT + c * 16 + lr] = bf16_1(acc[c][r] * di);
        }
    }
}

// Layer-1 aggregate: 128 bf16 cols/row, one wave per node, 16-deep gather ladder.
__global__ __launch_bounds__(256) void agg1_kernel(const unsigned* __restrict__ Gb,
                                                   const int* __restrict__ offs,
                                                   const int* __restrict__ csr,
                                                   const float* __restrict__ dinv,
                                                   const float* __restrict__ bias,
                                                   unsigned* __restrict__ outb, int N) {
    int node = (blockIdx.x * blockDim.x + threadIdx.x) >> 6;
    int lane = threadIdx.x & 63;
    if (node >= N) return;
    int e = offs[node];
    const int end = offs[node + 1];
    unsigned sv = Gb[(size_t)node * 64 + lane];
    float ax = bf16_lo(sv), ay = bf16_hi(sv);
    for (; e + 16 <= end; e += 16) {
        int j[16];
#pragma unroll
        for (int q = 0; q < 16; ++q) j[q] = csr[e + q];
        unsigned v[16];
#pragma unroll
        for (int q = 0; q < 16; ++q) v[q] = Gb[(size_t)j[q] * 64 + lane];
#pragma unroll
        for (int q = 0; q < 16; ++q) { ax += bf16_lo(v[q]); ay += bf16_hi(v[q]); }
    }
    for (; e + 8 <= end; e += 8) {
        int j[8];
#pragma unroll
        for (int q = 0; q < 8; ++q) j[q] = csr[e + q];
        unsigned v[8];
#pragma unroll
        for (int q = 0; q < 8; ++q) v[q] = Gb[(size_t)j[q] * 64 + lane];
#pragma unroll
        for (int q = 0; q < 8; ++q) { ax += bf16_lo(v[q]); ay += bf16_hi(v[q]); }
    }
    for (; e + 4 <= end; e += 4) {
        int j0 = csr[e], j1 = csr[e + 1], j2 = csr[e + 2], j3 = csr[e + 3];
        unsigned v0 = Gb[(size_t)j0 * 64 + lane];
        unsigned v1 = Gb[(size_t)j1 * 64 + lane];
        unsigned v2 = Gb[(size_t)j2 * 64 + lane];
        unsigned v3 = Gb[(size_t)j3 * 64 + lane];
        ax += bf16_lo(v0) + bf16_lo(v1) + bf16_lo(v2) + bf16_lo(v3);
        ay += bf16_hi(v0) + bf16_hi(v1) + bf16_hi(v2) + bf16_hi(v3);
    }
    for (; e < end; ++e) {
        unsigned v = Gb[(size_t)csr[e] * 64 + lane];
        ax += bf16_lo(v); ay += bf16_hi(v);
    }
    float di = dinv[node];
    float ox = fmaxf(ax * di + bias[lane * 2 + 0], 0.f);
    float oy = fmaxf(ay * di + bias[lane * 2 + 1], 0.f);
    outb[(size_t)node * 64 + lane] = pack_bf16_2(ox, oy);
}

// Layer-2 aggregate: 64 bf16 cols/row = 32 uints; two nodes per wave; 16-deep ladder.
__global__ __launch_bounds__(256) void agg2_kernel(const unsigned* __restrict__ Gb,
                                                   const int* __restrict__ offs,
                                                   const int* __restrict__ csr,
                                                   const float* __restrict__ dinv,
                                                   const float* __restrict__ bias,
                                                   float* __restrict__ out, int N) {
    int tid = blockIdx.x * blockDim.x + threadIdx.x;
    int node = (tid >> 6) * 2 + ((threadIdx.x >> 5) & 1);
    int c = threadIdx.x & 31;
    if (node >= N) return;
    int e = offs[node];
    const int end = offs[node + 1];
    unsigned sv = Gb[(size_t)node * 32 + c];
    float ax = bf16_lo(sv), ay = bf16_hi(sv);
    for (; e + 16 <= end; e += 16) {
        int j[16];
#pragma unroll
        for (int q = 0; q < 16; ++q) j[q] = csr[e + q];
        unsigned v[16];
#pragma unroll
        for (int q = 0; q < 16; ++q) v[q] = Gb[(size_t)j[q] * 32 + c];
#pragma unroll
        for (int q = 0; q < 16; ++q) { ax += bf16_lo(v[q]); ay += bf16_hi(v[q]); }
    }
    for (; e + 8 <= end; e += 8) {
        int j[8];
#pragma unroll
        for (int q = 0; q < 8; ++q) j[q] = csr[e + q];
        unsigned v[8];
#pragma unroll
        for (int q = 0; q < 8; ++q) v[q] = Gb[(size_t)j[q] * 32 + c];
#pragma unroll
        for (int q = 0; q < 8; ++q) { ax += bf16_lo(v[q]); ay += bf16_hi(v[q]); }
    }
    for (; e + 4 <= end; e += 4) {
        int j0 = csr[e], j1 = csr[e + 1], j2 = csr[e + 2], j3 = csr[e + 3];
        unsigned v0 = Gb[(size_t)j0 * 32 + c];
        unsigned v1 = Gb[(size_t)j1 * 32 + c];
        unsigned v2 = Gb[(size_t)j2 * 32 + c];
        unsigned v3 = Gb[(size_t)j3 * 32 + c];
        ax += bf16_lo(v0) + bf16_lo(v1) + bf16_lo(v2) + bf16_lo(v3);
        ay += bf16_hi(v0) + bf16_hi(v1) + bf16_hi(v2) + bf16_hi(v3);
    }
    for (; e < end; ++e) {
        unsigned v = Gb[(size_t)csr[e] * 32 + c];
        ax += bf16_lo(v); ay += bf16_hi(v);
    }
    float di = dinv[node];
    float2 o;
    o.x = ax * di + bias[c * 2 + 0];
    o.y = ay * di + bias[c * 2 + 1];
    *reinterpret_cast<float2*>(&out[(size_t)node * 64 + c * 2]) = o;
}

extern "C" void kernel_launch(void* const* d_in, const int* in_sizes, int n_in,
                              void* d_out, int out_size, void* d_ws, size_t ws_size,
                              hipStream_t stream) {
    const float* x  = (const float*)d_in[0];
    const int*   ei = (const int*)d_in[1];
    const float* W1 = (const float*)d_in[2];
    const float* b1 = (const float*)d_in[3];
    const float* W2 = (const float*)d_in[4];
    const float* b2 = (const float*)d_in[5];
    float* out = (float*)d_out;

    const int N = in_sizes[0] / 128;
    const int E = in_sizes[1] / 2;
    const int* src = ei;
    const int* dst = ei + E;
    const int nbkt = (N + 1023) >> 10;               // must be <= 256
    const int cap = E / nbkt + E / (4 * nbkt) + 1024; // ~37 sigma headroom for uniform dst

    // Workspace layout
    unsigned* g1b = (unsigned*)d_ws;                 // N*64 uints (25.6MB); reused as g2b
    unsigned* a1b = g1b + (size_t)N * 64;            // N*64 uints bf16 a1
    unsigned* g2b = g1b;
    int2* ebuf = (int2*)d_ws;                        // nbkt*cap*8B, aliases g1b (lifetime-disjoint)
    char* p = (char*)(a1b + (size_t)N * 64);
    float* dinv = (float*)p; p += (((size_t)N * 4) + 15) & ~(size_t)15;
    int* offs = (int*)p;   p += (((size_t)(N + 1) * 4) + 15) & ~(size_t)15;
    int* csr = (int*)p;    p += (((size_t)E * 4) + 15) & ~(size_t)15;
    int* bcur = (int*)p;   p += (((size_t)256 * 4) + 15) & ~(size_t)15;
    if ((size_t)(p - (char*)d_ws) > ws_size || nbkt > 256 ||
        (size_t)nbkt * cap * 8 > (size_t)N * 64 * 4) return;  // fail loudly

    // --- graph preprocessing (3 dispatches) ---
    hipMemsetAsync(bcur, 0, 256 * sizeof(int), stream);
    partition_fixed<<<(E + 4095) / 4096, 256, 0, stream>>>(src, dst, bcur, ebuf, E, nbkt, cap);
    csr_build<<<nbkt, 256, 0, stream>>>(ebuf, bcur, offs, dinv, csr, N, E, nbkt, cap);

    // --- layer 1 ---
    gemm_mfma<128, false><<<(N + 63) / 64, 256, 0, stream>>>(
        x, W1, dinv, (unsigned short*)g1b, N);
    agg1_kernel<<<(N + 3) / 4, 256, 0, stream>>>(g1b, offs, csr, dinv, b1, a1b, N);

    // --- layer 2 ---
    gemm_mfma<64, true><<<(N + 63) / 64, 256, 0, stream>>>(
        a1b, W2, dinv, (unsigned short*)g2b, N);
    agg2_kernel<<<(N + 7) / 8, 256, 0, stream>>>(g2b, offs, csr, dinv, b2, out, N);
}